// Round 10
// baseline (1249.390 us; speedup 1.0000x reference)
//
#include <hip/hip_runtime.h>

// ---------------------------------------------------------------------------
// LSTM + Bahdanau attention, MI355X (gfx950)
// B=32, T=256, IN=256, HID=512, ATTN=64, OUT=7
// ---------------------------------------------------------------------------

typedef _Float16 f16;
typedef _Float16 f16x4 __attribute__((ext_vector_type(4)));
typedef _Float16 f16x8 __attribute__((ext_vector_type(8)));
typedef float    f32x4 __attribute__((ext_vector_type(4)));

#define MFMA16(a, b, c) __builtin_amdgcn_mfma_f32_16x16x32_f16((a), (b), (c), 0, 0, 0)

__device__ __forceinline__ float sigm_f(float x) { return 1.f / (1.f + __expf(-x)); }
__device__ __forceinline__ float tanh_f(float x) { return 1.f - 2.f / (1.f + __expf(2.f * x)); }

// ws offsets (bytes)
#define OFF_XG    0ull            // f32 [256][32][2048]  = 67108864  (t, b, gate-row p)
#define OFF_CTX   0ull            // f32 [32][256][512]   = 16777216  (over Xg, Xg dead after K2)
#define OFF_LSTM  67108864ull     // f32 [32][256][512]   = 16777216
#define OFF_FEATS 83886080ull     // f32 [32][256][128]   = 4194304
#define OFF_LT16  88080384ull     // f16 [32][512][256]   = 8388608
#define OFF_HPK   96468992ull     // u32 [2][32][512]     = 131072  (packed hh|hl H, tagged)
#define WS_NEEDED 96731392ull

// ---------------------------------------------------------------------------
// K1: Xg[t][b][p] = sum_k Wih[r(p)][k]*emb[ids[b][t]][k] + bih[r]+bhh[r]
//     p = w*32 + q*8 + u  <->  r = q*512 + 8*w + u   (w = blockIdx.y)
// ---------------------------------------------------------------------------
__global__ __launch_bounds__(256) void k1_xg(const int* __restrict__ ids,
                                             const float* __restrict__ emb,
                                             const float* __restrict__ Wih,
                                             const float* __restrict__ bih,
                                             const float* __restrict__ bhh,
                                             float* __restrict__ Xg)
{
    __shared__ f16   xs[32 * 264];     // x tile   [b][k], pad +8 f16
    __shared__ f16   wsl[32 * 264];    // Wih tile [p_local][k]
    __shared__ float biasl[32];
    __shared__ int   idsl[32];
    __shared__ float outb[32 * 33];    // [p_local][b] staging
    const int tid = threadIdx.x;
    const int tb = blockIdx.x, w = blockIdx.y;

    // stage Wih slice (32 rows x 256) as f16
    for (int i = 0; i < 8; ++i) {
        int L4 = tid + i * 256;              // 2048 float4
        int row = L4 >> 6, k4 = L4 & 63;
        int r = (row >> 3) * 512 + 8 * w + (row & 7);
        float4 v = *(const float4*)(Wih + (size_t)r * 256 + k4 * 4);
        f16x4 h = { (f16)v.x, (f16)v.y, (f16)v.z, (f16)v.w };
        *(f16x4*)(wsl + row * 264 + k4 * 4) = h;
    }
    if (tid < 32) {
        int r = (tid >> 3) * 512 + 8 * w + (tid & 7);
        biasl[tid] = bih[r] + bhh[r];
    }

    const int wv = tid >> 6, l = tid & 63;
    const int mt = wv >> 1, nt = wv & 1;
    const int ar = (l & 15) + mt * 16;
    const int bc = (l & 15) + nt * 16;
    const int kc = (l >> 4) * 8;

    for (int tt = 0; tt < 8; ++tt) {
        int t = tb * 8 + tt;
        __syncthreads();                     // W staged / prev iter consumed
        if (tid < 32) idsl[tid] = ids[tid * 256 + t];
        __syncthreads();
        for (int i = 0; i < 8; ++i) {
            int L4 = tid + i * 256;
            int b = L4 >> 6, k4 = L4 & 63;
            float4 v = *(const float4*)(emb + (size_t)idsl[b] * 256 + k4 * 4);
            f16x4 h = { (f16)v.x, (f16)v.y, (f16)v.z, (f16)v.w };
            *(f16x4*)(xs + b * 264 + k4 * 4) = h;
        }
        __syncthreads();

        f32x4 acc = { 0.f, 0.f, 0.f, 0.f };
#pragma unroll
        for (int ks = 0; ks < 8; ++ks) {
            f16x8 a  = *(const f16x8*)(xs  + ar * 264 + ks * 32 + kc);
            f16x8 bf = *(const f16x8*)(wsl + bc * 264 + ks * 32 + kc);
            acc = MFMA16(a, bf, acc);
        }
        float bb = biasl[bc];
#pragma unroll
        for (int r = 0; r < 4; ++r)
            outb[bc * 33 + mt * 16 + (l >> 4) * 4 + r] = acc[r] + bb;
        __syncthreads();
        {   // store [t][b][p] (transposed): thread = (b = tid>>3, pq = tid&7)
            int b = tid >> 3, pq = tid & 7;
            float4 v = { outb[(pq * 4 + 0) * 33 + b], outb[(pq * 4 + 1) * 33 + b],
                         outb[(pq * 4 + 2) * 33 + b], outb[(pq * 4 + 3) * 33 + b] };
            *(float4*)(Xg + (size_t)t * 65536 + b * 2048 + w * 32 + pq * 4) = v;
        }
    }
}

// ---------------------------------------------------------------------------
// K2: LSTM recurrence, tagged-data protocol + SENTINEL poll (round-10).
// 32 persistent WGs x 512 threads; WG w owns units [16w,16w+16) (64 gate
// rows). Whh fragments in REGISTERS (hi + 4096*residual f16). Waves =
// (mt in 2, kq in 4): wave loads a DISJOINT 16-row x 128-col H slice.
// H = packed dwords  d = ((hl_bits & ~1) | tag) << 16 | hh_bits,
// tag = ((t+1)>>1)&1, ping-pong buffer, sc0 sc1 L3-coherent accesses.
// Poll is two-stage, BOTH single-hop:
//   (1) sentinel: 1 dword/lane; the 64 lanes span 8 rows x all 8 producer-WG
//       column blocks of this wave's quarter (256 B/wave/round vs 8 KB).
//   (2) bulk: full slice load, every dword tag-CHECKED (re-load if any
//       stale) -- identical to the proven round-6 loop, so correctness and
//       termination are unchanged; sentinel only gates when bulk starts.
// Init per launch: buf0=0x00 (tag0 = genuine H(0)=0), buf1=0xFF (tag1 blocks
// step 1). Fixed per-wave poll regions + <=1-step skew => deadlock-free.
// ---------------------------------------------------------------------------
__global__ __launch_bounds__(512) void k2_lstm(const float* __restrict__ Whh,
                                               const float* __restrict__ Xg,
                                               unsigned int* __restrict__ Hpk,
                                               float* __restrict__ lstm_out)
{
    __shared__ float pre[4 * 64 * 36]; // [kq][p_local][sample], pad 36 (2-way free)
    const int tid = threadIdx.x;
    const int w = blockIdx.x;

    const int u16 = tid & 15, s_up = tid >> 4;        // update lane = (unit, sample)
    const int wv = tid >> 6, l = tid & 63;
    const int mt = wv >> 2, kq = wv & 3;              // wave = (m-tile, k-quarter)
    const int li = l & 15, lh = l >> 4;
    const int arow = mt * 16 + li;                    // sample row for A-fragment
    const int kcol = lh * 8;

    // ---- one-time: Whh fragments into registers (64 rows x 128 cols / wave) ----
    f16x8 bh[4][4], bl[4][4];                         // [ks][nt]
#pragma unroll
    for (int ks = 0; ks < 4; ++ks) {
#pragma unroll
        for (int nt = 0; nt < 4; ++nt) {
            int pl = nt * 16 + li;                    // p_local 0..63
            int q = (pl & 31) >> 3, u8 = pl & 7, wp = pl >> 5;
            int r = q * 512 + 16 * w + 8 * wp + u8;   // global gate row
            const float* s0 = Whh + (size_t)r * 512 + kq * 128 + ks * 32 + kcol;
            float4 v0 = *(const float4*)(s0);
            float4 v1 = *(const float4*)(s0 + 4);
            float vv[8] = { v0.x, v0.y, v0.z, v0.w, v1.x, v1.y, v1.z, v1.w };
            f16x8 hi, lo;
#pragma unroll
            for (int j = 0; j < 8; ++j) {
                hi[j] = (f16)vv[j];
                lo[j] = (f16)((vv[j] - (float)hi[j]) * 4096.f);
            }
            bh[ks][nt] = hi; bl[ks][nt] = lo;
        }
    }

    // ---- Xg offsets for the update thread's 4 gates; prefetch t=0 ----
    int xoff[4];
    float xg_c[4], xg_n[4];
#pragma unroll
    for (int q = 0; q < 4; ++q) {
        int pl = 32 * (u16 >> 3) + 8 * q + (u16 & 7);
        xoff[q] = s_up * 2048 + 64 * w + pl;
        xg_c[q] = Xg[xoff[q]];                        // t = 0
    }

    float c = 0.f;

    for (int t = 0; t < 256; ++t) {
        const int rbuf = t & 1;
        const unsigned e = (unsigned)((t >> 1) & 1);
        const unsigned int* Hr = Hpk + rbuf * 16384 + arow * 512 + kq * 128 + kcol;

        // ---- (1) sentinel poll: 1 dword/lane, spans all 8 producer WGs ----
        {
            const unsigned int* sp = Hpk + rbuf * 16384
                                   + (mt * 16 + ((l >> 3) << 1)) * 512
                                   + kq * 128 + (l & 7) * 16 + 15;
            for (;;) {
                unsigned sv;
                asm volatile("global_load_dword %0, %1, off sc0 sc1\n\t"
                             "s_waitcnt vmcnt(0)"
                             : "=v"(sv) : "v"(sp) : "memory");
                if (__all(((sv >> 16) & 1u) == e)) break;
                __builtin_amdgcn_s_sleep(1);
            }
            __builtin_amdgcn_sched_barrier(0);
        }

        // ---- (2) bulk load + verify (every consumed dword tag-checked) ----
        float4 P[4], Q[4];
        for (;;) {
#pragma unroll
            for (int ks = 0; ks < 4; ++ks) {
                asm volatile("global_load_dwordx4 %0, %1, off sc0 sc1"
                             : "=v"(P[ks]) : "v"(Hr + ks * 32));
                asm volatile("global_load_dwordx4 %0, %1, off sc0 sc1"
                             : "=v"(Q[ks]) : "v"(Hr + ks * 32 + 4));
            }
            asm volatile("s_waitcnt vmcnt(0)" ::: "memory");
            __builtin_amdgcn_sched_barrier(0);
            unsigned av = 0xFFFFFFFFu, ov = 0u;
#pragma unroll
            for (int ks = 0; ks < 4; ++ks) {
                unsigned m0 = __float_as_uint(P[ks].x) & __float_as_uint(P[ks].y)
                            & __float_as_uint(P[ks].z) & __float_as_uint(P[ks].w);
                unsigned m1 = __float_as_uint(Q[ks].x) & __float_as_uint(Q[ks].y)
                            & __float_as_uint(Q[ks].z) & __float_as_uint(Q[ks].w);
                unsigned o0 = __float_as_uint(P[ks].x) | __float_as_uint(P[ks].y)
                            | __float_as_uint(P[ks].z) | __float_as_uint(P[ks].w);
                unsigned o1 = __float_as_uint(Q[ks].x) | __float_as_uint(Q[ks].y)
                            | __float_as_uint(Q[ks].z) | __float_as_uint(Q[ks].w);
                av &= m0 & m1;
                ov |= o0 | o1;
            }
            bool fresh = e ? (((av >> 16) & 1u) == 1u) : (((ov >> 16) & 1u) == 0u);
            if (__all(fresh)) break;
        }

        // ---- prefetch Xg for t+1 (plain loads; consumed next iteration) ----
        {
            int tn = (t < 255) ? t + 1 : 255;
            const float* xb = Xg + (size_t)tn * 65536;
#pragma unroll
            for (int q = 0; q < 4; ++q) xg_n[q] = xb[xoff[q]];
        }

        // ---- unpack + MFMA over this wave's K-quarter ----
        f32x4 acc1[4], acc2[4];
#pragma unroll
        for (int nt = 0; nt < 4; ++nt) { acc1[nt] = (f32x4){0,0,0,0}; acc2[nt] = (f32x4){0,0,0,0}; }
#pragma unroll
        for (int ks = 0; ks < 4; ++ks) {
            unsigned p0 = __float_as_uint(P[ks].x), p1 = __float_as_uint(P[ks].y),
                     p2 = __float_as_uint(P[ks].z), p3 = __float_as_uint(P[ks].w),
                     q0 = __float_as_uint(Q[ks].x), q1 = __float_as_uint(Q[ks].y),
                     q2 = __float_as_uint(Q[ks].z), q3 = __float_as_uint(Q[ks].w);
            uint4 hi4 = { __builtin_amdgcn_perm(p1, p0, 0x05040100u),
                          __builtin_amdgcn_perm(p3, p2, 0x05040100u),
                          __builtin_amdgcn_perm(q1, q0, 0x05040100u),
                          __builtin_amdgcn_perm(q3, q2, 0x05040100u) };
            uint4 lo4 = { __builtin_amdgcn_perm(p1, p0, 0x07060302u),
                          __builtin_amdgcn_perm(p3, p2, 0x07060302u),
                          __builtin_amdgcn_perm(q1, q0, 0x07060302u),
                          __builtin_amdgcn_perm(q3, q2, 0x07060302u) };
            f16x8 a1 = __builtin_bit_cast(f16x8, hi4);
            f16x8 a2 = __builtin_bit_cast(f16x8, lo4);
#pragma unroll
            for (int nt = 0; nt < 4; ++nt) {
                acc1[nt] = MFMA16(a1, bh[ks][nt], acc1[nt]);
                acc2[nt] = MFMA16(a2, bh[ks][nt], acc2[nt]);
                acc2[nt] = MFMA16(a1, bl[ks][nt], acc2[nt]);
            }
        }

        __syncthreads();                 // prev update done everywhere (pre free)
#pragma unroll
        for (int nt = 0; nt < 4; ++nt) {
            f32x4 v;
#pragma unroll
            for (int r = 0; r < 4; ++r) v[r] = acc1[nt][r] + acc2[nt][r] * (1.f / 4096.f);
            *(f32x4*)(pre + (kq * 64 + nt * 16 + li) * 36 + mt * 16 + lh * 4) = v;
        }
        __syncthreads();

        {   // ---- state update: thread = (u16, s_up) ----
            float z[4];
#pragma unroll
            for (int q = 0; q < 4; ++q) {
                int pl = 32 * (u16 >> 3) + 8 * q + (u16 & 7);
                z[q] = pre[(0 * 64 + pl) * 36 + s_up] + pre[(1 * 64 + pl) * 36 + s_up]
                     + pre[(2 * 64 + pl) * 36 + s_up] + pre[(3 * 64 + pl) * 36 + s_up]
                     + xg_c[q];
            }
            float ig = sigm_f(z[0]), fg = sigm_f(z[1]);
            float gg = tanh_f(z[2]), og = sigm_f(z[3]);
            c = fg * c + ig * gg;
            float h = og * tanh_f(c);
            f16 hh = (f16)h;
            f16 hl = (f16)((h - (float)hh) * 4096.f);
            int uu = 16 * w + u16;
            if (t < 255) {
                unsigned hhb = (unsigned)__builtin_bit_cast(unsigned short, hh);
                unsigned hlb = (unsigned)__builtin_bit_cast(unsigned short, hl);
                unsigned wtag = (unsigned)(((t + 1) >> 1) & 1);
                unsigned d = (((hlb & 0xFFFEu) | wtag) << 16) | hhb;
                asm volatile("global_store_dword %0, %1, off sc0 sc1"
                             :: "v"(Hpk + ((t + 1) & 1) * 16384 + s_up * 512 + uu),
                                "v"(d) : "memory");
            }
            lstm_out[((size_t)s_up * 256 + t) * 512 + uu] = h;
        }
#pragma unroll
        for (int q = 0; q < 4; ++q) xg_c[q] = xg_n[q];
    }
}

// ---------------------------------------------------------------------------
// K3: feats[bt][0:64]=lstm@We.T+be ; feats[bt][64:128]=lstm@Wd.T+bd
// ---------------------------------------------------------------------------
__global__ __launch_bounds__(256) void k3_feats(const float* __restrict__ lstm_out,
                                                const float* __restrict__ We,
                                                const float* __restrict__ be,
                                                const float* __restrict__ Wd,
                                                const float* __restrict__ bd,
                                                float* __restrict__ feats)
{
    __shared__ f16 xs[32 * 520];       // [m][k] full K=512
    __shared__ f16 wsl[128 * 264];     // [n][k-chunk 256]
    const int tid = threadIdx.x;
    const int bt0 = blockIdx.x * 32;

    for (int i = 0; i < 16; ++i) {
        int L4 = tid + i * 256;
        int row = L4 >> 7, k4 = L4 & 127;
        float4 v = *(const float4*)(lstm_out + (size_t)(bt0 + row) * 512 + k4 * 4);
        f16x4 h = { (f16)v.x, (f16)v.y, (f16)v.z, (f16)v.w };
        *(f16x4*)(xs + row * 520 + k4 * 4) = h;
    }
    const int wv = tid >> 6, l = tid & 63;
    const int mt = wv >> 1, ng = (wv & 1) * 4;
    f32x4 acc[4];
#pragma unroll
    for (int j = 0; j < 4; ++j) acc[j] = (f32x4){0,0,0,0};

    for (int kc = 0; kc < 2; ++kc) {
        __syncthreads();                 // xs ready / prev chunk consumed
        for (int i = 0; i < 32; ++i) {
            int L4 = tid + i * 256;      // 8192 float4
            int row = L4 >> 6, k4 = L4 & 63;
            const float* src = (row < 64) ? (We + (size_t)row * 512)
                                          : (Wd + (size_t)(row - 64) * 512);
            float4 v = *(const float4*)(src + kc * 256 + k4 * 4);
            f16x4 h = { (f16)v.x, (f16)v.y, (f16)v.z, (f16)v.w };
            *(f16x4*)(wsl + row * 264 + k4 * 4) = h;
        }
        __syncthreads();
#pragma unroll
        for (int ks = 0; ks < 8; ++ks) {
            int kk = ks * 32 + (l >> 4) * 8;
            f16x8 a = *(const f16x8*)(xs + (mt * 16 + (l & 15)) * 520 + kc * 256 + kk);
#pragma unroll
            for (int j = 0; j < 4; ++j) {
                f16x8 bf = *(const f16x8*)(wsl + ((ng + j) * 16 + (l & 15)) * 264 + kk);
                acc[j] = MFMA16(a, bf, acc[j]);
            }
        }
    }
    int m0 = mt * 16 + (l >> 4) * 4;
#pragma unroll
    for (int j = 0; j < 4; ++j) {
        int n = (ng + j) * 16 + (l & 15);
        float bb = (n < 64) ? be[n] : bd[n - 64];
#pragma unroll
        for (int r = 0; r < 4; ++r)
            feats[(size_t)(bt0 + m0 + r) * 128 + n] = acc[j][r] + bb;
    }
}

// ---------------------------------------------------------------------------
// K3b: lstm_out [b][t][512] f32 -> lstmT16 [b][512][256] f16
// ---------------------------------------------------------------------------
__global__ __launch_bounds__(256) void k3b_tr(const float* __restrict__ lstm_out,
                                              f16* __restrict__ lstmT)
{
    __shared__ f16 tile[64 * 72];
    const int tid = threadIdx.x;
    const int bid = blockIdx.x;          // 32*8*4
    const int b = bid >> 5;
    const int rem = bid & 31;
    const int h0 = (rem >> 2) * 64, t0 = (rem & 3) * 64;

    for (int i = 0; i < 4; ++i) {
        int L4 = tid + i * 256;
        int tr = L4 >> 4, h4 = L4 & 15;
        float4 v = *(const float4*)(lstm_out + ((size_t)b * 256 + t0 + tr) * 512 + h0 + h4 * 4);
        f16x4 h = { (f16)v.x, (f16)v.y, (f16)v.z, (f16)v.w };
        *(f16x4*)(tile + tr * 72 + h4 * 4) = h;
    }
    __syncthreads();
    int hr = tid >> 2, tseg = (tid & 3) * 16;
    f16x8 o0, o1;
#pragma unroll
    for (int j = 0; j < 8; ++j) {
        o0[j] = tile[(tseg + j) * 72 + hr];
        o1[j] = tile[(tseg + 8 + j) * 72 + hr];
    }
    f16* dst = lstmT + ((size_t)b * 512 + h0 + hr) * 256 + t0 + tseg;
    *(f16x8*)(dst) = o0;
    *(f16x8*)(dst + 8) = o1;
}

// ---------------------------------------------------------------------------
// K4: scores = v.tanh(dec[t]+enc[e]) + vb -> softmax(e) -> ctx = P @ lstm
// WG = (b, 32-row t-tile)
// ---------------------------------------------------------------------------
__global__ __launch_bounds__(256, 1) void k4_attn(const float* __restrict__ feats,
                                                  const f16* __restrict__ lstmT,
                                                  const float* __restrict__ vvec,
                                                  const float* __restrict__ vb,
                                                  float* __restrict__ ctx)
{
    __shared__ float encf[64 * 260];   // [a][e] (transposed) -- reused as ctxs[32][516]
    __shared__ float decf[32 * 68];    // [t][a]
    __shared__ f16   p16[32 * 264];    // [t][e]
    __shared__ float vs[64];
    __shared__ float vbs;
    const int tid = threadIdx.x;
    const int b = blockIdx.x >> 3, tt = blockIdx.x & 7;
    const int t0 = tt * 32;

    for (int i = 0; i < 16; ++i) {
        int L4 = tid + i * 256;          // 4096 float4 of enc feats
        int e = L4 >> 4, a4 = (L4 & 15) * 4;
        float4 v = *(const float4*)(feats + ((size_t)b * 256 + e) * 128 + a4);
        encf[(a4 + 0) * 260 + e] = v.x;  // transpose to [a][e]
        encf[(a4 + 1) * 260 + e] = v.y;
        encf[(a4 + 2) * 260 + e] = v.z;
        encf[(a4 + 3) * 260 + e] = v.w;
    }
    for (int i = 0; i < 2; ++i) {
        int L4 = tid + i * 256;
        int tr = L4 >> 4, a4 = (L4 & 15) * 4;
        float4 v = *(const float4*)(feats + ((size_t)b * 256 + t0 + tr) * 128 + 64 + a4);
        *(float4*)(decf + tr * 68 + a4) = v;
    }
    if (tid < 64) vs[tid] = vvec[tid];
    if (tid == 0) vbs = vb[0];
    __syncthreads();

    const int wv = tid >> 6, l = tid & 63;
    // ---- scores + softmax: one wave per t-row ----
    for (int tr = wv; tr < 32; tr += 4) {
        float sc[4];
#pragma unroll
        for (int j = 0; j < 4; ++j) {
            int e = l + j * 64;
            float s = vbs;
            for (int a = 0; a < 64; ++a) {
                float x = decf[tr * 68 + a] + encf[a * 260 + e];
                s += vs[a] * (1.f - 2.f / (1.f + __expf(2.f * x)));
            }
            sc[j] = s;
        }
        float mx = fmaxf(fmaxf(sc[0], sc[1]), fmaxf(sc[2], sc[3]));
        for (int d = 1; d < 64; d <<= 1) mx = fmaxf(mx, __shfl_xor(mx, d));
        float sm = 0.f;
#pragma unroll
        for (int j = 0; j < 4; ++j) { sc[j] = __expf(sc[j] - mx); sm += sc[j]; }
        for (int d = 1; d < 64; d <<= 1) sm += __shfl_xor(sm, d);
        float inv = 1.f / sm;
#pragma unroll
        for (int j = 0; j < 4; ++j) p16[tr * 264 + l + j * 64] = (f16)(sc[j] * inv);
    }
    __syncthreads();

    // ---- context MFMA: M=32(t) N=512(h) K=256(e); wave=(kh, n-half) ----
    const int kh = wv & 1, nth = wv >> 1;
    f32x4 acc0[16], acc1[16];
#pragma unroll
    for (int j = 0; j < 16; ++j) { acc0[j] = (f32x4){0,0,0,0}; acc1[j] = (f32x4){0,0,0,0}; }
#pragma unroll
    for (int ks = 0; ks < 4; ++ks) {
        int kk = (kh * 4 + ks) * 32 + (l >> 4) * 8;
        f16x8 a0 = *(const f16x8*)(p16 + (l & 15) * 264 + kk);
        f16x8 a1 = *(const f16x8*)(p16 + ((l & 15) + 16) * 264 + kk);
#pragma unroll
        for (int j = 0; j < 16; ++j) {
            int n = (nth * 16 + j) * 16 + (l & 15);
            f16x8 bf = *(const f16x8*)(lstmT + ((size_t)b * 512 + n) * 256 + kk);
            acc0[j] = MFMA16(a0, bf, acc0[j]);
            acc1[j] = MFMA16(a1, bf, acc1[j]);
        }
    }
    float* ctxs = encf;                  // reuse (encf dead now)
    __syncthreads();
    const int m0 = (l >> 4) * 4, nn = (l & 15);
    if (kh == 0) {
#pragma unroll
        for (int j = 0; j < 16; ++j) {
            int n = (nth * 16 + j) * 16 + nn;
#pragma unroll
            for (int r = 0; r < 4; ++r) {
                ctxs[(m0 + r) * 516 + n]      = acc0[j][r];
                ctxs[(16 + m0 + r) * 516 + n] = acc1[j][r];
            }
        }
    }
    __syncthreads();
    if (kh == 1) {
#pragma unroll
        for (int j = 0; j < 16; ++j) {
            int n = (nth * 16 + j) * 16 + nn;
#pragma unroll
            for (int r = 0; r < 4; ++r) {
                ctxs[(m0 + r) * 516 + n]      += acc0[j][r];
                ctxs[(16 + m0 + r) * 516 + n] += acc1[j][r];
            }
        }
    }
    __syncthreads();
    for (int i = 0; i < 16; ++i) {
        int flat = (tid + i * 256) * 4;  // 16384 floats
        int m = flat >> 9, h = flat & 511;
        float4 v = *(const float4*)(ctxs + m * 516 + h);
        *(float4*)(ctx + ((size_t)b * 256 + t0 + m) * 512 + h) = v;
    }
}

// ---------------------------------------------------------------------------
// K5: logits = [lstm, ctx] @ Wfc.T + bfc
// ---------------------------------------------------------------------------
__global__ __launch_bounds__(256) void k5_fc(const float* __restrict__ lstm_out,
                                             const float* __restrict__ ctx,
                                             const float* __restrict__ Wfc,
                                             const float* __restrict__ bfc,
                                             float* __restrict__ out)
{
    const int tid = threadIdx.x;
    const int b = blockIdx.x >> 3, tt = blockIdx.x & 7;
    const int tr = tid >> 3, o = tid & 7;
    if (o >= 7) return;
    const int t = tt * 32 + tr;
    float acc = bfc[o];
    const float* xl = lstm_out + ((size_t)b * 256 + t) * 512;
    const float* xc = ctx + ((size_t)b * 256 + t) * 512;
    const float* w1 = Wfc + (size_t)o * 1024;
    for (int k = 0; k < 512; k += 4) {
        float4 xv = *(const float4*)(xl + k);
        float4 wv = *(const float4*)(w1 + k);
        acc += xv.x * wv.x + xv.y * wv.y + xv.z * wv.z + xv.w * wv.w;
    }
    for (int k = 0; k < 512; k += 4) {
        float4 xv = *(const float4*)(xc + k);
        float4 wv = *(const float4*)(w1 + 512 + k);
        acc += xv.x * wv.x + xv.y * wv.y + xv.z * wv.z + xv.w * wv.w;
    }
    out[((size_t)b * 256 + t) * 7 + o] = acc;
}

// ---------------------------------------------------------------------------
extern "C" void kernel_launch(void* const* d_in, const int* in_sizes, int n_in,
                              void* d_out, int out_size, void* d_ws, size_t ws_size,
                              hipStream_t stream)
{
    (void)in_sizes; (void)n_in; (void)out_size;
    if (ws_size < WS_NEEDED) return;  // would fail validation loudly, not corrupt

    const int*   ids = (const int*)d_in[0];
    const float* emb = (const float*)d_in[1];
    const float* Wih = (const float*)d_in[2];
    const float* Whh = (const float*)d_in[3];
    const float* bih = (const float*)d_in[4];
    const float* bhh = (const float*)d_in[5];
    const float* We  = (const float*)d_in[6];
    const float* be  = (const float*)d_in[7];
    const float* Wd  = (const float*)d_in[8];
    const float* bd  = (const float*)d_in[9];
    const float* vv  = (const float*)d_in[10];
    const float* vb  = (const float*)d_in[11];
    const float* Wfc = (const float*)d_in[12];
    const float* bfc = (const float*)d_in[13];

    char* ws = (char*)d_ws;
    float* Xg    = (float*)(ws + OFF_XG);
    float* ctx   = (float*)(ws + OFF_CTX);
    float* lstm  = (float*)(ws + OFF_LSTM);
    float* feats = (float*)(ws + OFF_FEATS);
    f16*   lstmT = (f16*)(ws + OFF_LT16);
    unsigned int* Hpk = (unsigned int*)(ws + OFF_HPK);

    // Tag-safe init EVERY launch (also clears cross-replay staleness):
    //   buf0 = 0x00... -> tag 0 AND the genuine H(0)=0 input for step 0
    //   buf1 = 0xFF... -> tag 1, which step 1 (expecting tag 0) must wait out
    hipMemsetAsync(Hpk,          0x00, 65536, stream);
    hipMemsetAsync(Hpk + 16384,  0xFF, 65536, stream);

    k1_xg   <<<dim3(32, 64), 256, 0, stream>>>(ids, emb, Wih, bih, bhh, Xg);
    k2_lstm <<<dim3(32),     512, 0, stream>>>(Whh, Xg, Hpk, lstm);
    k3_feats<<<dim3(256),    256, 0, stream>>>(lstm, We, be, Wd, bd, feats);
    k3b_tr  <<<dim3(1024),   256, 0, stream>>>(lstm, lstmT);
    k4_attn <<<dim3(256),    256, 0, stream>>>(feats, lstmT, vv, vb, ctx);
    k5_fc   <<<dim3(256),    256, 0, stream>>>(lstm, ctx, Wfc, bfc, (float*)d_out);
}

// Round 11
// 1131.582 us; speedup vs baseline: 1.1041x; 1.1041x over previous
//
#include <hip/hip_runtime.h>

// ---------------------------------------------------------------------------
// LSTM + Bahdanau attention, MI355X (gfx950)
// B=32, T=256, IN=256, HID=512, ATTN=64, OUT=7
// ---------------------------------------------------------------------------

typedef _Float16 f16;
typedef _Float16 f16x4 __attribute__((ext_vector_type(4)));
typedef _Float16 f16x8 __attribute__((ext_vector_type(8)));
typedef float    f32x4 __attribute__((ext_vector_type(4)));

#define MFMA16(a, b, c) __builtin_amdgcn_mfma_f32_16x16x32_f16((a), (b), (c), 0, 0, 0)

__device__ __forceinline__ float sigm_f(float x) { return 1.f / (1.f + __expf(-x)); }
__device__ __forceinline__ float tanh_f(float x) { return 1.f - 2.f / (1.f + __expf(2.f * x)); }

// ws offsets (bytes)
#define OFF_XG    0ull            // f32 [256][32][2048]  = 67108864  (t, b, gate-row p)
#define OFF_CTX   0ull            // f32 [32][256][512]   = 16777216  (over Xg, Xg dead after K2)
#define OFF_LSTM  67108864ull     // f32 [32][256][512]   = 16777216
#define OFF_FEATS 83886080ull     // f32 [32][256][128]   = 4194304
#define OFF_LT16  88080384ull     // f16 [32][512][256]   = 8388608
#define OFF_HPK   96468992ull     // u32 [2][32][512]     = 131072  (packed hh|hl H, tagged)
#define WS_NEEDED 96731392ull

// ---------------------------------------------------------------------------
// K1: Xg[t][b][p] = sum_k Wih[r(p)][k]*emb[ids[b][t]][k] + bih[r]+bhh[r]
//     p = w*32 + q*8 + u  <->  r = q*512 + 8*w + u   (w = blockIdx.y)
// ---------------------------------------------------------------------------
__global__ __launch_bounds__(256) void k1_xg(const int* __restrict__ ids,
                                             const float* __restrict__ emb,
                                             const float* __restrict__ Wih,
                                             const float* __restrict__ bih,
                                             const float* __restrict__ bhh,
                                             float* __restrict__ Xg)
{
    __shared__ f16   xs[32 * 264];     // x tile   [b][k], pad +8 f16
    __shared__ f16   wsl[32 * 264];    // Wih tile [p_local][k]
    __shared__ float biasl[32];
    __shared__ int   idsl[32];
    __shared__ float outb[32 * 33];    // [p_local][b] staging
    const int tid = threadIdx.x;
    const int tb = blockIdx.x, w = blockIdx.y;

    // stage Wih slice (32 rows x 256) as f16
    for (int i = 0; i < 8; ++i) {
        int L4 = tid + i * 256;              // 2048 float4
        int row = L4 >> 6, k4 = L4 & 63;
        int r = (row >> 3) * 512 + 8 * w + (row & 7);
        float4 v = *(const float4*)(Wih + (size_t)r * 256 + k4 * 4);
        f16x4 h = { (f16)v.x, (f16)v.y, (f16)v.z, (f16)v.w };
        *(f16x4*)(wsl + row * 264 + k4 * 4) = h;
    }
    if (tid < 32) {
        int r = (tid >> 3) * 512 + 8 * w + (tid & 7);
        biasl[tid] = bih[r] + bhh[r];
    }

    const int wv = tid >> 6, l = tid & 63;
    const int mt = wv >> 1, nt = wv & 1;
    const int ar = (l & 15) + mt * 16;
    const int bc = (l & 15) + nt * 16;
    const int kc = (l >> 4) * 8;

    for (int tt = 0; tt < 8; ++tt) {
        int t = tb * 8 + tt;
        __syncthreads();                     // W staged / prev iter consumed
        if (tid < 32) idsl[tid] = ids[tid * 256 + t];
        __syncthreads();
        for (int i = 0; i < 8; ++i) {
            int L4 = tid + i * 256;
            int b = L4 >> 6, k4 = L4 & 63;
            float4 v = *(const float4*)(emb + (size_t)idsl[b] * 256 + k4 * 4);
            f16x4 h = { (f16)v.x, (f16)v.y, (f16)v.z, (f16)v.w };
            *(f16x4*)(xs + b * 264 + k4 * 4) = h;
        }
        __syncthreads();

        f32x4 acc = { 0.f, 0.f, 0.f, 0.f };
#pragma unroll
        for (int ks = 0; ks < 8; ++ks) {
            f16x8 a  = *(const f16x8*)(xs  + ar * 264 + ks * 32 + kc);
            f16x8 bf = *(const f16x8*)(wsl + bc * 264 + ks * 32 + kc);
            acc = MFMA16(a, bf, acc);
        }
        float bb = biasl[bc];
#pragma unroll
        for (int r = 0; r < 4; ++r)
            outb[bc * 33 + mt * 16 + (l >> 4) * 4 + r] = acc[r] + bb;
        __syncthreads();
        {   // store [t][b][p] (transposed): thread = (b = tid>>3, pq = tid&7)
            int b = tid >> 3, pq = tid & 7;
            float4 v = { outb[(pq * 4 + 0) * 33 + b], outb[(pq * 4 + 1) * 33 + b],
                         outb[(pq * 4 + 2) * 33 + b], outb[(pq * 4 + 3) * 33 + b] };
            *(float4*)(Xg + (size_t)t * 65536 + b * 2048 + w * 32 + pq * 4) = v;
        }
    }
}

// ---------------------------------------------------------------------------
// K2: LSTM recurrence, tagged-data protocol (round-6/9 proven config) with
// DOUBLE-BUFFERED pre LDS -> single barrier per step.
// 32 persistent WGs x 512 threads; WG w owns units [16w,16w+16) (64 gate
// rows). Whh fragments in REGISTERS (hi + 4096*residual f16). Waves =
// (mt in 2, kq in 4): wave polls/loads a DISJOINT 16-row x 128-col H slice.
// H = packed dwords  d = ((hl_bits & ~1) | tag) << 16 | hh_bits,
// tag = ((t+1)>>1)&1, ping-pong buffer; consumers poll the data itself
// (per-dword tag) with sc0 sc1 L3-coherent loads. Combined detect+fetch =
// ONE L3 traversal (rounds 7/10 proved added hops regress).
// Init per launch: buf0=0x00 (tag0 = genuine H(0)=0), buf1=0xFF (tag1 blocks
// step 1). Fixed per-wave poll regions + <=1-step skew => deadlock-free.
// Barrier analysis (single sync): the remaining barrier orders pre-writes ->
// pre-reads (RAW) and couples all waves before any update-phase H store (the
// skew argument's requirement). The dropped barrier only guarded WAR on pre,
// now removed by the (t&1) ping-pong: step t reads pre[t&1] while step t+1
// writes pre[(t+1)&1]; step t+2's writes to pre[t&1] are ordered after step
// t's reads by the step-t+1 barrier.
// ---------------------------------------------------------------------------
__global__ __launch_bounds__(512) void k2_lstm(const float* __restrict__ Whh,
                                               const float* __restrict__ Xg,
                                               unsigned int* __restrict__ Hpk,
                                               float* __restrict__ lstm_out)
{
    __shared__ float pre[2][4 * 64 * 36]; // [buf][kq][p_local][sample], pad 36
    const int tid = threadIdx.x;
    const int w = blockIdx.x;

    const int u16 = tid & 15, s_up = tid >> 4;        // update lane = (unit, sample)
    const int wv = tid >> 6, l = tid & 63;
    const int mt = wv >> 2, kq = wv & 3;              // wave = (m-tile, k-quarter)
    const int li = l & 15, lh = l >> 4;
    const int arow = mt * 16 + li;                    // sample row for A-fragment
    const int kcol = lh * 8;

    // ---- one-time: Whh fragments into registers (64 rows x 128 cols / wave) ----
    f16x8 bh[4][4], bl[4][4];                         // [ks][nt]
#pragma unroll
    for (int ks = 0; ks < 4; ++ks) {
#pragma unroll
        for (int nt = 0; nt < 4; ++nt) {
            int pl = nt * 16 + li;                    // p_local 0..63
            int q = (pl & 31) >> 3, u8 = pl & 7, wp = pl >> 5;
            int r = q * 512 + 16 * w + 8 * wp + u8;   // global gate row
            const float* s0 = Whh + (size_t)r * 512 + kq * 128 + ks * 32 + kcol;
            float4 v0 = *(const float4*)(s0);
            float4 v1 = *(const float4*)(s0 + 4);
            float vv[8] = { v0.x, v0.y, v0.z, v0.w, v1.x, v1.y, v1.z, v1.w };
            f16x8 hi, lo;
#pragma unroll
            for (int j = 0; j < 8; ++j) {
                hi[j] = (f16)vv[j];
                lo[j] = (f16)((vv[j] - (float)hi[j]) * 4096.f);
            }
            bh[ks][nt] = hi; bl[ks][nt] = lo;
        }
    }

    // ---- Xg offsets for the update thread's 4 gates; prefetch t=0 ----
    int xoff[4];
    float xg_c[4], xg_n[4];
#pragma unroll
    for (int q = 0; q < 4; ++q) {
        int pl = 32 * (u16 >> 3) + 8 * q + (u16 & 7);
        xoff[q] = s_up * 2048 + 64 * w + pl;
        xg_c[q] = Xg[xoff[q]];                        // t = 0
    }

    float c = 0.f;

    for (int t = 0; t < 256; ++t) {
        const int rbuf = t & 1;
        const unsigned e = (unsigned)((t >> 1) & 1);
        const unsigned int* Hr = Hpk + rbuf * 16384 + arow * 512 + kq * 128 + kcol;
        float* prebuf = pre[t & 1];

        // ---- poll-and-load: re-load this wave's slice until all tags == e ----
        float4 P[4], Q[4];
        for (;;) {
#pragma unroll
            for (int ks = 0; ks < 4; ++ks) {
                asm volatile("global_load_dwordx4 %0, %1, off sc0 sc1"
                             : "=v"(P[ks]) : "v"(Hr + ks * 32));
                asm volatile("global_load_dwordx4 %0, %1, off sc0 sc1"
                             : "=v"(Q[ks]) : "v"(Hr + ks * 32 + 4));
            }
            asm volatile("s_waitcnt vmcnt(0)" ::: "memory");
            __builtin_amdgcn_sched_barrier(0);
            unsigned av = 0xFFFFFFFFu, ov = 0u;
#pragma unroll
            for (int ks = 0; ks < 4; ++ks) {
                unsigned m0 = __float_as_uint(P[ks].x) & __float_as_uint(P[ks].y)
                            & __float_as_uint(P[ks].z) & __float_as_uint(P[ks].w);
                unsigned m1 = __float_as_uint(Q[ks].x) & __float_as_uint(Q[ks].y)
                            & __float_as_uint(Q[ks].z) & __float_as_uint(Q[ks].w);
                unsigned o0 = __float_as_uint(P[ks].x) | __float_as_uint(P[ks].y)
                            | __float_as_uint(P[ks].z) | __float_as_uint(P[ks].w);
                unsigned o1 = __float_as_uint(Q[ks].x) | __float_as_uint(Q[ks].y)
                            | __float_as_uint(Q[ks].z) | __float_as_uint(Q[ks].w);
                av &= m0 & m1;
                ov |= o0 | o1;
            }
            bool fresh = e ? (((av >> 16) & 1u) == 1u) : (((ov >> 16) & 1u) == 0u);
            if (__all(fresh)) break;
            __builtin_amdgcn_s_sleep(1);
        }

        // ---- prefetch Xg for t+1 (plain loads; consumed next iteration) ----
        {
            int tn = (t < 255) ? t + 1 : 255;
            const float* xb = Xg + (size_t)tn * 65536;
#pragma unroll
            for (int q = 0; q < 4; ++q) xg_n[q] = xb[xoff[q]];
        }

        // ---- unpack + MFMA over this wave's K-quarter ----
        f32x4 acc1[4], acc2[4];
#pragma unroll
        for (int nt = 0; nt < 4; ++nt) { acc1[nt] = (f32x4){0,0,0,0}; acc2[nt] = (f32x4){0,0,0,0}; }
#pragma unroll
        for (int ks = 0; ks < 4; ++ks) {
            unsigned p0 = __float_as_uint(P[ks].x), p1 = __float_as_uint(P[ks].y),
                     p2 = __float_as_uint(P[ks].z), p3 = __float_as_uint(P[ks].w),
                     q0 = __float_as_uint(Q[ks].x), q1 = __float_as_uint(Q[ks].y),
                     q2 = __float_as_uint(Q[ks].z), q3 = __float_as_uint(Q[ks].w);
            uint4 hi4 = { __builtin_amdgcn_perm(p1, p0, 0x05040100u),
                          __builtin_amdgcn_perm(p3, p2, 0x05040100u),
                          __builtin_amdgcn_perm(q1, q0, 0x05040100u),
                          __builtin_amdgcn_perm(q3, q2, 0x05040100u) };
            uint4 lo4 = { __builtin_amdgcn_perm(p1, p0, 0x07060302u),
                          __builtin_amdgcn_perm(p3, p2, 0x07060302u),
                          __builtin_amdgcn_perm(q1, q0, 0x07060302u),
                          __builtin_amdgcn_perm(q3, q2, 0x07060302u) };
            f16x8 a1 = __builtin_bit_cast(f16x8, hi4);
            f16x8 a2 = __builtin_bit_cast(f16x8, lo4);
#pragma unroll
            for (int nt = 0; nt < 4; ++nt) {
                acc1[nt] = MFMA16(a1, bh[ks][nt], acc1[nt]);
                acc2[nt] = MFMA16(a2, bh[ks][nt], acc2[nt]);
                acc2[nt] = MFMA16(a1, bl[ks][nt], acc2[nt]);
            }
        }

        // ---- stage pre-activations into this step's LDS buffer ----
#pragma unroll
        for (int nt = 0; nt < 4; ++nt) {
            f32x4 v;
#pragma unroll
            for (int r = 0; r < 4; ++r) v[r] = acc1[nt][r] + acc2[nt][r] * (1.f / 4096.f);
            *(f32x4*)(prebuf + (kq * 64 + nt * 16 + li) * 36 + mt * 16 + lh * 4) = v;
        }
        __syncthreads();                 // pre[buf] visible; couples waves pre-store

        {   // ---- state update: thread = (u16, s_up) ----
            float z[4];
#pragma unroll
            for (int q = 0; q < 4; ++q) {
                int pl = 32 * (u16 >> 3) + 8 * q + (u16 & 7);
                z[q] = prebuf[(0 * 64 + pl) * 36 + s_up] + prebuf[(1 * 64 + pl) * 36 + s_up]
                     + prebuf[(2 * 64 + pl) * 36 + s_up] + prebuf[(3 * 64 + pl) * 36 + s_up]
                     + xg_c[q];
            }
            float ig = sigm_f(z[0]), fg = sigm_f(z[1]);
            float gg = tanh_f(z[2]), og = sigm_f(z[3]);
            c = fg * c + ig * gg;
            float h = og * tanh_f(c);
            f16 hh = (f16)h;
            f16 hl = (f16)((h - (float)hh) * 4096.f);
            int uu = 16 * w + u16;
            if (t < 255) {
                unsigned hhb = (unsigned)__builtin_bit_cast(unsigned short, hh);
                unsigned hlb = (unsigned)__builtin_bit_cast(unsigned short, hl);
                unsigned wtag = (unsigned)(((t + 1) >> 1) & 1);
                unsigned d = (((hlb & 0xFFFEu) | wtag) << 16) | hhb;
                asm volatile("global_store_dword %0, %1, off sc0 sc1"
                             :: "v"(Hpk + ((t + 1) & 1) * 16384 + s_up * 512 + uu),
                                "v"(d) : "memory");
            }
            lstm_out[((size_t)s_up * 256 + t) * 512 + uu] = h;
        }
#pragma unroll
        for (int q = 0; q < 4; ++q) xg_c[q] = xg_n[q];
    }
}

// ---------------------------------------------------------------------------
// K3: feats[bt][0:64]=lstm@We.T+be ; feats[bt][64:128]=lstm@Wd.T+bd
// ---------------------------------------------------------------------------
__global__ __launch_bounds__(256) void k3_feats(const float* __restrict__ lstm_out,
                                                const float* __restrict__ We,
                                                const float* __restrict__ be,
                                                const float* __restrict__ Wd,
                                                const float* __restrict__ bd,
                                                float* __restrict__ feats)
{
    __shared__ f16 xs[32 * 520];       // [m][k] full K=512
    __shared__ f16 wsl[128 * 264];     // [n][k-chunk 256]
    const int tid = threadIdx.x;
    const int bt0 = blockIdx.x * 32;

    for (int i = 0; i < 16; ++i) {
        int L4 = tid + i * 256;
        int row = L4 >> 7, k4 = L4 & 127;
        float4 v = *(const float4*)(lstm_out + (size_t)(bt0 + row) * 512 + k4 * 4);
        f16x4 h = { (f16)v.x, (f16)v.y, (f16)v.z, (f16)v.w };
        *(f16x4*)(xs + row * 520 + k4 * 4) = h;
    }
    const int wv = tid >> 6, l = tid & 63;
    const int mt = wv >> 1, ng = (wv & 1) * 4;
    f32x4 acc[4];
#pragma unroll
    for (int j = 0; j < 4; ++j) acc[j] = (f32x4){0,0,0,0};

    for (int kc = 0; kc < 2; ++kc) {
        __syncthreads();                 // xs ready / prev chunk consumed
        for (int i = 0; i < 32; ++i) {
            int L4 = tid + i * 256;      // 8192 float4
            int row = L4 >> 6, k4 = L4 & 63;
            const float* src = (row < 64) ? (We + (size_t)row * 512)
                                          : (Wd + (size_t)(row - 64) * 512);
            float4 v = *(const float4*)(src + kc * 256 + k4 * 4);
            f16x4 h = { (f16)v.x, (f16)v.y, (f16)v.z, (f16)v.w };
            *(f16x4*)(wsl + row * 264 + k4 * 4) = h;
        }
        __syncthreads();
#pragma unroll
        for (int ks = 0; ks < 8; ++ks) {
            int kk = ks * 32 + (l >> 4) * 8;
            f16x8 a = *(const f16x8*)(xs + (mt * 16 + (l & 15)) * 520 + kc * 256 + kk);
#pragma unroll
            for (int j = 0; j < 4; ++j) {
                f16x8 bf = *(const f16x8*)(wsl + ((ng + j) * 16 + (l & 15)) * 264 + kk);
                acc[j] = MFMA16(a, bf, acc[j]);
            }
        }
    }
    int m0 = mt * 16 + (l >> 4) * 4;
#pragma unroll
    for (int j = 0; j < 4; ++j) {
        int n = (ng + j) * 16 + (l & 15);
        float bb = (n < 64) ? be[n] : bd[n - 64];
#pragma unroll
        for (int r = 0; r < 4; ++r)
            feats[(size_t)(bt0 + m0 + r) * 128 + n] = acc[j][r] + bb;
    }
}

// ---------------------------------------------------------------------------
// K3b: lstm_out [b][t][512] f32 -> lstmT16 [b][512][256] f16
// ---------------------------------------------------------------------------
__global__ __launch_bounds__(256) void k3b_tr(const float* __restrict__ lstm_out,
                                              f16* __restrict__ lstmT)
{
    __shared__ f16 tile[64 * 72];
    const int tid = threadIdx.x;
    const int bid = blockIdx.x;          // 32*8*4
    const int b = bid >> 5;
    const int rem = bid & 31;
    const int h0 = (rem >> 2) * 64, t0 = (rem & 3) * 64;

    for (int i = 0; i < 4; ++i) {
        int L4 = tid + i * 256;
        int tr = L4 >> 4, h4 = L4 & 15;
        float4 v = *(const float4*)(lstm_out + ((size_t)b * 256 + t0 + tr) * 512 + h0 + h4 * 4);
        f16x4 h = { (f16)v.x, (f16)v.y, (f16)v.z, (f16)v.w };
        *(f16x4*)(tile + tr * 72 + h4 * 4) = h;
    }
    __syncthreads();
    int hr = tid >> 2, tseg = (tid & 3) * 16;
    f16x8 o0, o1;
#pragma unroll
    for (int j = 0; j < 8; ++j) {
        o0[j] = tile[(tseg + j) * 72 + hr];
        o1[j] = tile[(tseg + 8 + j) * 72 + hr];
    }
    f16* dst = lstmT + ((size_t)b * 512 + h0 + hr) * 256 + t0 + tseg;
    *(f16x8*)(dst) = o0;
    *(f16x8*)(dst + 8) = o1;
}

// ---------------------------------------------------------------------------
// K4: scores = v.tanh(dec[t]+enc[e]) + vb -> softmax(e) -> ctx = P @ lstm
// WG = (b, 32-row t-tile)
// ---------------------------------------------------------------------------
__global__ __launch_bounds__(256, 1) void k4_attn(const float* __restrict__ feats,
                                                  const f16* __restrict__ lstmT,
                                                  const float* __restrict__ vvec,
                                                  const float* __restrict__ vb,
                                                  float* __restrict__ ctx)
{
    __shared__ float encf[64 * 260];   // [a][e] (transposed) -- reused as ctxs[32][516]
    __shared__ float decf[32 * 68];    // [t][a]
    __shared__ f16   p16[32 * 264];    // [t][e]
    __shared__ float vs[64];
    __shared__ float vbs;
    const int tid = threadIdx.x;
    const int b = blockIdx.x >> 3, tt = blockIdx.x & 7;
    const int t0 = tt * 32;

    for (int i = 0; i < 16; ++i) {
        int L4 = tid + i * 256;          // 4096 float4 of enc feats
        int e = L4 >> 4, a4 = (L4 & 15) * 4;
        float4 v = *(const float4*)(feats + ((size_t)b * 256 + e) * 128 + a4);
        encf[(a4 + 0) * 260 + e] = v.x;  // transpose to [a][e]
        encf[(a4 + 1) * 260 + e] = v.y;
        encf[(a4 + 2) * 260 + e] = v.z;
        encf[(a4 + 3) * 260 + e] = v.w;
    }
    for (int i = 0; i < 2; ++i) {
        int L4 = tid + i * 256;
        int tr = L4 >> 4, a4 = (L4 & 15) * 4;
        float4 v = *(const float4*)(feats + ((size_t)b * 256 + t0 + tr) * 128 + 64 + a4);
        *(float4*)(decf + tr * 68 + a4) = v;
    }
    if (tid < 64) vs[tid] = vvec[tid];
    if (tid == 0) vbs = vb[0];
    __syncthreads();

    const int wv = tid >> 6, l = tid & 63;
    // ---- scores + softmax: one wave per t-row ----
    for (int tr = wv; tr < 32; tr += 4) {
        float sc[4];
#pragma unroll
        for (int j = 0; j < 4; ++j) {
            int e = l + j * 64;
            float s = vbs;
            for (int a = 0; a < 64; ++a) {
                float x = decf[tr * 68 + a] + encf[a * 260 + e];
                s += vs[a] * (1.f - 2.f / (1.f + __expf(2.f * x)));
            }
            sc[j] = s;
        }
        float mx = fmaxf(fmaxf(sc[0], sc[1]), fmaxf(sc[2], sc[3]));
        for (int d = 1; d < 64; d <<= 1) mx = fmaxf(mx, __shfl_xor(mx, d));
        float sm = 0.f;
#pragma unroll
        for (int j = 0; j < 4; ++j) { sc[j] = __expf(sc[j] - mx); sm += sc[j]; }
        for (int d = 1; d < 64; d <<= 1) sm += __shfl_xor(sm, d);
        float inv = 1.f / sm;
#pragma unroll
        for (int j = 0; j < 4; ++j) p16[tr * 264 + l + j * 64] = (f16)(sc[j] * inv);
    }
    __syncthreads();

    // ---- context MFMA: M=32(t) N=512(h) K=256(e); wave=(kh, n-half) ----
    const int kh = wv & 1, nth = wv >> 1;
    f32x4 acc0[16], acc1[16];
#pragma unroll
    for (int j = 0; j < 16; ++j) { acc0[j] = (f32x4){0,0,0,0}; acc1[j] = (f32x4){0,0,0,0}; }
#pragma unroll
    for (int ks = 0; ks < 4; ++ks) {
        int kk = (kh * 4 + ks) * 32 + (l >> 4) * 8;
        f16x8 a0 = *(const f16x8*)(p16 + (l & 15) * 264 + kk);
        f16x8 a1 = *(const f16x8*)(p16 + ((l & 15) + 16) * 264 + kk);
#pragma unroll
        for (int j = 0; j < 16; ++j) {
            int n = (nth * 16 + j) * 16 + (l & 15);
            f16x8 bf = *(const f16x8*)(lstmT + ((size_t)b * 512 + n) * 256 + kk);
            acc0[j] = MFMA16(a0, bf, acc0[j]);
            acc1[j] = MFMA16(a1, bf, acc1[j]);
        }
    }
    float* ctxs = encf;                  // reuse (encf dead now)
    __syncthreads();
    const int m0 = (l >> 4) * 4, nn = (l & 15);
    if (kh == 0) {
#pragma unroll
        for (int j = 0; j < 16; ++j) {
            int n = (nth * 16 + j) * 16 + nn;
#pragma unroll
            for (int r = 0; r < 4; ++r) {
                ctxs[(m0 + r) * 516 + n]      = acc0[j][r];
                ctxs[(16 + m0 + r) * 516 + n] = acc1[j][r];
            }
        }
    }
    __syncthreads();
    if (kh == 1) {
#pragma unroll
        for (int j = 0; j < 16; ++j) {
            int n = (nth * 16 + j) * 16 + nn;
#pragma unroll
            for (int r = 0; r < 4; ++r) {
                ctxs[(m0 + r) * 516 + n]      += acc0[j][r];
                ctxs[(16 + m0 + r) * 516 + n] += acc1[j][r];
            }
        }
    }
    __syncthreads();
    for (int i = 0; i < 16; ++i) {
        int flat = (tid + i * 256) * 4;  // 16384 floats
        int m = flat >> 9, h = flat & 511;
        float4 v = *(const float4*)(ctxs + m * 516 + h);
        *(float4*)(ctx + ((size_t)b * 256 + t0 + m) * 512 + h) = v;
    }
}

// ---------------------------------------------------------------------------
// K5: logits = [lstm, ctx] @ Wfc.T + bfc
// ---------------------------------------------------------------------------
__global__ __launch_bounds__(256) void k5_fc(const float* __restrict__ lstm_out,
                                             const float* __restrict__ ctx,
                                             const float* __restrict__ Wfc,
                                             const float* __restrict__ bfc,
                                             float* __restrict__ out)
{
    const int tid = threadIdx.x;
    const int b = blockIdx.x >> 3, tt = blockIdx.x & 7;
    const int tr = tid >> 3, o = tid & 7;
    if (o >= 7) return;
    const int t = tt * 32 + tr;
    float acc = bfc[o];
    const float* xl = lstm_out + ((size_t)b * 256 + t) * 512;
    const float* xc = ctx + ((size_t)b * 256 + t) * 512;
    const float* w1 = Wfc + (size_t)o * 1024;
    for (int k = 0; k < 512; k += 4) {
        float4 xv = *(const float4*)(xl + k);
        float4 wv = *(const float4*)(w1 + k);
        acc += xv.x * wv.x + xv.y * wv.y + xv.z * wv.z + xv.w * wv.w;
    }
    for (int k = 0; k < 512; k += 4) {
        float4 xv = *(const float4*)(xc + k);
        float4 wv = *(const float4*)(w1 + 512 + k);
        acc += xv.x * wv.x + xv.y * wv.y + xv.z * wv.z + xv.w * wv.w;
    }
    out[((size_t)b * 256 + t) * 7 + o] = acc;
}

// ---------------------------------------------------------------------------
extern "C" void kernel_launch(void* const* d_in, const int* in_sizes, int n_in,
                              void* d_out, int out_size, void* d_ws, size_t ws_size,
                              hipStream_t stream)
{
    (void)in_sizes; (void)n_in; (void)out_size;
    if (ws_size < WS_NEEDED) return;  // would fail validation loudly, not corrupt

    const int*   ids = (const int*)d_in[0];
    const float* emb = (const float*)d_in[1];
    const float* Wih = (const float*)d_in[2];
    const float* Whh = (const float*)d_in[3];
    const float* bih = (const float*)d_in[4];
    const float* bhh = (const float*)d_in[5];
    const float* We  = (const float*)d_in[6];
    const float* be  = (const float*)d_in[7];
    const float* Wd  = (const float*)d_in[8];
    const float* bd  = (const float*)d_in[9];
    const float* vv  = (const float*)d_in[10];
    const float* vb  = (const float*)d_in[11];
    const float* Wfc = (const float*)d_in[12];
    const float* bfc = (const float*)d_in[13];

    char* ws = (char*)d_ws;
    float* Xg    = (float*)(ws + OFF_XG);
    float* ctx   = (float*)(ws + OFF_CTX);
    float* lstm  = (float*)(ws + OFF_LSTM);
    float* feats = (float*)(ws + OFF_FEATS);
    f16*   lstmT = (f16*)(ws + OFF_LT16);
    unsigned int* Hpk = (unsigned int*)(ws + OFF_HPK);

    // Tag-safe init EVERY launch (also clears cross-replay staleness):
    //   buf0 = 0x00... -> tag 0 AND the genuine H(0)=0 input for step 0
    //   buf1 = 0xFF... -> tag 1, which step 1 (expecting tag 0) must wait out
    hipMemsetAsync(Hpk,          0x00, 65536, stream);
    hipMemsetAsync(Hpk + 16384,  0xFF, 65536, stream);

    k1_xg   <<<dim3(32, 64), 256, 0, stream>>>(ids, emb, Wih, bih, bhh, Xg);
    k2_lstm <<<dim3(32),     512, 0, stream>>>(Whh, Xg, Hpk, lstm);
    k3_feats<<<dim3(256),    256, 0, stream>>>(lstm, We, be, Wd, bd, feats);
    k3b_tr  <<<dim3(1024),   256, 0, stream>>>(lstm, lstmT);
    k4_attn <<<dim3(256),    256, 0, stream>>>(feats, lstmT, vv, vb, ctx);
    k5_fc   <<<dim3(256),    256, 0, stream>>>(lstm, ctx, Wfc, bfc, (float*)d_out);
}

// Round 12
// 1121.198 us; speedup vs baseline: 1.1143x; 1.0093x over previous
//
#include <hip/hip_runtime.h>

// ---------------------------------------------------------------------------
// LSTM + Bahdanau attention, MI355X (gfx950)
// B=32, T=256, IN=256, HID=512, ATTN=64, OUT=7
// ---------------------------------------------------------------------------

typedef _Float16 f16;
typedef _Float16 f16x4 __attribute__((ext_vector_type(4)));
typedef _Float16 f16x8 __attribute__((ext_vector_type(8)));
typedef float    f32x4 __attribute__((ext_vector_type(4)));

#define MFMA16(a, b, c) __builtin_amdgcn_mfma_f32_16x16x32_f16((a), (b), (c), 0, 0, 0)

__device__ __forceinline__ float sigm_f(float x) { return 1.f / (1.f + __expf(-x)); }
__device__ __forceinline__ float tanh_f(float x) { return 1.f - 2.f / (1.f + __expf(2.f * x)); }

// ws offsets (bytes)
#define OFF_XG    0ull            // f32 [256][32][2048]  = 67108864  (t, b, gate-row p)
#define OFF_LSTM  67108864ull     // f32 [32][256][512]   = 16777216
#define OFF_FEATS 83886080ull     // f32 [32][256][128]   = 4194304
#define OFF_LT16  88080384ull     // f16 [32][512][256]   = 8388608
#define OFF_HPK   96468992ull     // u32 [2][32][512]     = 131072  (packed hh|hl H, tagged)
#define WS_NEEDED 96731392ull

// ---------------------------------------------------------------------------
// K1: Xg[t][b][p] = sum_k Wih[r(p)][k]*emb[ids[b][t]][k] + bih[r]+bhh[r]
//     p = w*32 + q*8 + u  <->  r = q*512 + 8*w + u   (w = blockIdx.y)
// ---------------------------------------------------------------------------
__global__ __launch_bounds__(256) void k1_xg(const int* __restrict__ ids,
                                             const float* __restrict__ emb,
                                             const float* __restrict__ Wih,
                                             const float* __restrict__ bih,
                                             const float* __restrict__ bhh,
                                             float* __restrict__ Xg)
{
    __shared__ f16   xs[32 * 264];     // x tile   [b][k], pad +8 f16
    __shared__ f16   wsl[32 * 264];    // Wih tile [p_local][k]
    __shared__ float biasl[32];
    __shared__ int   idsl[32];
    __shared__ float outb[32 * 33];    // [p_local][b] staging
    const int tid = threadIdx.x;
    const int tb = blockIdx.x, w = blockIdx.y;

    // stage Wih slice (32 rows x 256) as f16
    for (int i = 0; i < 8; ++i) {
        int L4 = tid + i * 256;              // 2048 float4
        int row = L4 >> 6, k4 = L4 & 63;
        int r = (row >> 3) * 512 + 8 * w + (row & 7);
        float4 v = *(const float4*)(Wih + (size_t)r * 256 + k4 * 4);
        f16x4 h = { (f16)v.x, (f16)v.y, (f16)v.z, (f16)v.w };
        *(f16x4*)(wsl + row * 264 + k4 * 4) = h;
    }
    if (tid < 32) {
        int r = (tid >> 3) * 512 + 8 * w + (tid & 7);
        biasl[tid] = bih[r] + bhh[r];
    }

    const int wv = tid >> 6, l = tid & 63;
    const int mt = wv >> 1, nt = wv & 1;
    const int ar = (l & 15) + mt * 16;
    const int bc = (l & 15) + nt * 16;
    const int kc = (l >> 4) * 8;

    for (int tt = 0; tt < 8; ++tt) {
        int t = tb * 8 + tt;
        __syncthreads();                     // W staged / prev iter consumed
        if (tid < 32) idsl[tid] = ids[tid * 256 + t];
        __syncthreads();
        for (int i = 0; i < 8; ++i) {
            int L4 = tid + i * 256;
            int b = L4 >> 6, k4 = L4 & 63;
            float4 v = *(const float4*)(emb + (size_t)idsl[b] * 256 + k4 * 4);
            f16x4 h = { (f16)v.x, (f16)v.y, (f16)v.z, (f16)v.w };
            *(f16x4*)(xs + b * 264 + k4 * 4) = h;
        }
        __syncthreads();

        f32x4 acc = { 0.f, 0.f, 0.f, 0.f };
#pragma unroll
        for (int ks = 0; ks < 8; ++ks) {
            f16x8 a  = *(const f16x8*)(xs  + ar * 264 + ks * 32 + kc);
            f16x8 bf = *(const f16x8*)(wsl + bc * 264 + ks * 32 + kc);
            acc = MFMA16(a, bf, acc);
        }
        float bb = biasl[bc];
#pragma unroll
        for (int r = 0; r < 4; ++r)
            outb[bc * 33 + mt * 16 + (l >> 4) * 4 + r] = acc[r] + bb;
        __syncthreads();
        {   // store [t][b][p] (transposed): thread = (b = tid>>3, pq = tid&7)
            int b = tid >> 3, pq = tid & 7;
            float4 v = { outb[(pq * 4 + 0) * 33 + b], outb[(pq * 4 + 1) * 33 + b],
                         outb[(pq * 4 + 2) * 33 + b], outb[(pq * 4 + 3) * 33 + b] };
            *(float4*)(Xg + (size_t)t * 65536 + b * 2048 + w * 32 + pq * 4) = v;
        }
    }
}

// ---------------------------------------------------------------------------
// K2: LSTM recurrence, tagged-data protocol (locked config: round-6 protocol
// + pad-36 + double-buffered pre/single barrier). 32 persistent WGs x 512
// threads; WG w owns units [16w,16w+16) (64 gate rows). Whh fragments in
// REGISTERS (hi + 4096*residual f16). Waves = (mt in 2, kq in 4): wave
// polls/loads a DISJOINT 16-row x 128-col H slice.
// H = packed dwords  d = ((hl_bits & ~1) | tag) << 16 | hh_bits,
// tag = ((t+1)>>1)&1, ping-pong buffer; consumers poll the data itself
// (per-dword tag) with sc0 sc1 L3-coherent loads. Combined detect+fetch =
// ONE L3 traversal (rounds 7/10 proved added hops regress).
// Init per launch: buf0=0x00 (tag0 = genuine H(0)=0), buf1=0xFF (tag1 blocks
// step 1). Fixed per-wave poll regions + <=1-step skew => deadlock-free.
// ---------------------------------------------------------------------------
__global__ __launch_bounds__(512) void k2_lstm(const float* __restrict__ Whh,
                                               const float* __restrict__ Xg,
                                               unsigned int* __restrict__ Hpk,
                                               float* __restrict__ lstm_out)
{
    __shared__ float pre[2][4 * 64 * 36]; // [buf][kq][p_local][sample], pad 36
    const int tid = threadIdx.x;
    const int w = blockIdx.x;

    const int u16 = tid & 15, s_up = tid >> 4;        // update lane = (unit, sample)
    const int wv = tid >> 6, l = tid & 63;
    const int mt = wv >> 2, kq = wv & 3;              // wave = (m-tile, k-quarter)
    const int li = l & 15, lh = l >> 4;
    const int arow = mt * 16 + li;                    // sample row for A-fragment
    const int kcol = lh * 8;

    // ---- one-time: Whh fragments into registers (64 rows x 128 cols / wave) ----
    f16x8 bh[4][4], bl[4][4];                         // [ks][nt]
#pragma unroll
    for (int ks = 0; ks < 4; ++ks) {
#pragma unroll
        for (int nt = 0; nt < 4; ++nt) {
            int pl = nt * 16 + li;                    // p_local 0..63
            int q = (pl & 31) >> 3, u8 = pl & 7, wp = pl >> 5;
            int r = q * 512 + 16 * w + 8 * wp + u8;   // global gate row
            const float* s0 = Whh + (size_t)r * 512 + kq * 128 + ks * 32 + kcol;
            float4 v0 = *(const float4*)(s0);
            float4 v1 = *(const float4*)(s0 + 4);
            float vv[8] = { v0.x, v0.y, v0.z, v0.w, v1.x, v1.y, v1.z, v1.w };
            f16x8 hi, lo;
#pragma unroll
            for (int j = 0; j < 8; ++j) {
                hi[j] = (f16)vv[j];
                lo[j] = (f16)((vv[j] - (float)hi[j]) * 4096.f);
            }
            bh[ks][nt] = hi; bl[ks][nt] = lo;
        }
    }

    // ---- Xg offsets for the update thread's 4 gates; prefetch t=0 ----
    int xoff[4];
    float xg_c[4], xg_n[4];
#pragma unroll
    for (int q = 0; q < 4; ++q) {
        int pl = 32 * (u16 >> 3) + 8 * q + (u16 & 7);
        xoff[q] = s_up * 2048 + 64 * w + pl;
        xg_c[q] = Xg[xoff[q]];                        // t = 0
    }

    float c = 0.f;

    for (int t = 0; t < 256; ++t) {
        const int rbuf = t & 1;
        const unsigned e = (unsigned)((t >> 1) & 1);
        const unsigned int* Hr = Hpk + rbuf * 16384 + arow * 512 + kq * 128 + kcol;
        float* prebuf = pre[t & 1];

        // ---- poll-and-load: re-load this wave's slice until all tags == e ----
        float4 P[4], Q[4];
        for (;;) {
#pragma unroll
            for (int ks = 0; ks < 4; ++ks) {
                asm volatile("global_load_dwordx4 %0, %1, off sc0 sc1"
                             : "=v"(P[ks]) : "v"(Hr + ks * 32));
                asm volatile("global_load_dwordx4 %0, %1, off sc0 sc1"
                             : "=v"(Q[ks]) : "v"(Hr + ks * 32 + 4));
            }
            asm volatile("s_waitcnt vmcnt(0)" ::: "memory");
            __builtin_amdgcn_sched_barrier(0);
            unsigned av = 0xFFFFFFFFu, ov = 0u;
#pragma unroll
            for (int ks = 0; ks < 4; ++ks) {
                unsigned m0 = __float_as_uint(P[ks].x) & __float_as_uint(P[ks].y)
                            & __float_as_uint(P[ks].z) & __float_as_uint(P[ks].w);
                unsigned m1 = __float_as_uint(Q[ks].x) & __float_as_uint(Q[ks].y)
                            & __float_as_uint(Q[ks].z) & __float_as_uint(Q[ks].w);
                unsigned o0 = __float_as_uint(P[ks].x) | __float_as_uint(P[ks].y)
                            | __float_as_uint(P[ks].z) | __float_as_uint(P[ks].w);
                unsigned o1 = __float_as_uint(Q[ks].x) | __float_as_uint(Q[ks].y)
                            | __float_as_uint(Q[ks].z) | __float_as_uint(Q[ks].w);
                av &= m0 & m1;
                ov |= o0 | o1;
            }
            bool fresh = e ? (((av >> 16) & 1u) == 1u) : (((ov >> 16) & 1u) == 0u);
            if (__all(fresh)) break;
            __builtin_amdgcn_s_sleep(1);
        }

        // ---- prefetch Xg for t+1 (plain loads; consumed next iteration) ----
        {
            int tn = (t < 255) ? t + 1 : 255;
            const float* xb = Xg + (size_t)tn * 65536;
#pragma unroll
            for (int q = 0; q < 4; ++q) xg_n[q] = xb[xoff[q]];
        }

        // ---- unpack + MFMA over this wave's K-quarter ----
        f32x4 acc1[4], acc2[4];
#pragma unroll
        for (int nt = 0; nt < 4; ++nt) { acc1[nt] = (f32x4){0,0,0,0}; acc2[nt] = (f32x4){0,0,0,0}; }
#pragma unroll
        for (int ks = 0; ks < 4; ++ks) {
            unsigned p0 = __float_as_uint(P[ks].x), p1 = __float_as_uint(P[ks].y),
                     p2 = __float_as_uint(P[ks].z), p3 = __float_as_uint(P[ks].w),
                     q0 = __float_as_uint(Q[ks].x), q1 = __float_as_uint(Q[ks].y),
                     q2 = __float_as_uint(Q[ks].z), q3 = __float_as_uint(Q[ks].w);
            uint4 hi4 = { __builtin_amdgcn_perm(p1, p0, 0x05040100u),
                          __builtin_amdgcn_perm(p3, p2, 0x05040100u),
                          __builtin_amdgcn_perm(q1, q0, 0x05040100u),
                          __builtin_amdgcn_perm(q3, q2, 0x05040100u) };
            uint4 lo4 = { __builtin_amdgcn_perm(p1, p0, 0x07060302u),
                          __builtin_amdgcn_perm(p3, p2, 0x07060302u),
                          __builtin_amdgcn_perm(q1, q0, 0x07060302u),
                          __builtin_amdgcn_perm(q3, q2, 0x07060302u) };
            f16x8 a1 = __builtin_bit_cast(f16x8, hi4);
            f16x8 a2 = __builtin_bit_cast(f16x8, lo4);
#pragma unroll
            for (int nt = 0; nt < 4; ++nt) {
                acc1[nt] = MFMA16(a1, bh[ks][nt], acc1[nt]);
                acc2[nt] = MFMA16(a2, bh[ks][nt], acc2[nt]);
                acc2[nt] = MFMA16(a1, bl[ks][nt], acc2[nt]);
            }
        }

        // ---- stage pre-activations into this step's LDS buffer ----
#pragma unroll
        for (int nt = 0; nt < 4; ++nt) {
            f32x4 v;
#pragma unroll
            for (int r = 0; r < 4; ++r) v[r] = acc1[nt][r] + acc2[nt][r] * (1.f / 4096.f);
            *(f32x4*)(prebuf + (kq * 64 + nt * 16 + li) * 36 + mt * 16 + lh * 4) = v;
        }
        __syncthreads();                 // pre[buf] visible; couples waves pre-store

        {   // ---- state update: thread = (u16, s_up) ----
            float z[4];
#pragma unroll
            for (int q = 0; q < 4; ++q) {
                int pl = 32 * (u16 >> 3) + 8 * q + (u16 & 7);
                z[q] = prebuf[(0 * 64 + pl) * 36 + s_up] + prebuf[(1 * 64 + pl) * 36 + s_up]
                     + prebuf[(2 * 64 + pl) * 36 + s_up] + prebuf[(3 * 64 + pl) * 36 + s_up]
                     + xg_c[q];
            }
            float ig = sigm_f(z[0]), fg = sigm_f(z[1]);
            float gg = tanh_f(z[2]), og = sigm_f(z[3]);
            c = fg * c + ig * gg;
            float h = og * tanh_f(c);
            f16 hh = (f16)h;
            f16 hl = (f16)((h - (float)hh) * 4096.f);
            int uu = 16 * w + u16;
            if (t < 255) {
                unsigned hhb = (unsigned)__builtin_bit_cast(unsigned short, hh);
                unsigned hlb = (unsigned)__builtin_bit_cast(unsigned short, hl);
                unsigned wtag = (unsigned)(((t + 1) >> 1) & 1);
                unsigned d = (((hlb & 0xFFFEu) | wtag) << 16) | hhb;
                asm volatile("global_store_dword %0, %1, off sc0 sc1"
                             :: "v"(Hpk + ((t + 1) & 1) * 16384 + s_up * 512 + uu),
                                "v"(d) : "memory");
            }
            lstm_out[((size_t)s_up * 256 + t) * 512 + uu] = h;
        }
#pragma unroll
        for (int q = 0; q < 4; ++q) xg_c[q] = xg_n[q];
    }
}

// ---------------------------------------------------------------------------
// K3: feats[bt][0:64]=lstm@We.T+be ; feats[bt][64:128]=lstm@Wd.T+bd
// FUSED (round-12): also emits lstmT16 [b][h][t] from the already-staged xs
// f16 tile (same (f16) cast as the old K3b -> bit-identical lstmT).
// ---------------------------------------------------------------------------
__global__ __launch_bounds__(256) void k3_feats(const float* __restrict__ lstm_out,
                                                const float* __restrict__ We,
                                                const float* __restrict__ be,
                                                const float* __restrict__ Wd,
                                                const float* __restrict__ bd,
                                                float* __restrict__ feats,
                                                f16* __restrict__ lstmT)
{
    __shared__ f16 xs[32 * 520];       // [m][k] full K=512
    __shared__ f16 wsl[128 * 264];     // [n][k-chunk 256]
    const int tid = threadIdx.x;
    const int bt0 = blockIdx.x * 32;
    const int b = bt0 >> 8, t0 = bt0 & 255;

    for (int i = 0; i < 16; ++i) {
        int L4 = tid + i * 256;
        int row = L4 >> 7, k4 = L4 & 127;
        float4 v = *(const float4*)(lstm_out + (size_t)(bt0 + row) * 512 + k4 * 4);
        f16x4 h = { (f16)v.x, (f16)v.y, (f16)v.z, (f16)v.w };
        *(f16x4*)(xs + row * 520 + k4 * 4) = h;
    }
    const int wv = tid >> 6, l = tid & 63;
    const int mt = wv >> 1, ng = (wv & 1) * 4;
    f32x4 acc[4];
#pragma unroll
    for (int j = 0; j < 4; ++j) acc[j] = (f32x4){0,0,0,0};

    for (int kc = 0; kc < 2; ++kc) {
        __syncthreads();                 // xs ready / prev chunk consumed
        for (int i = 0; i < 32; ++i) {
            int L4 = tid + i * 256;      // 8192 float4
            int row = L4 >> 6, k4 = L4 & 63;
            const float* src = (row < 64) ? (We + (size_t)row * 512)
                                          : (Wd + (size_t)(row - 64) * 512);
            float4 v = *(const float4*)(src + kc * 256 + k4 * 4);
            f16x4 h = { (f16)v.x, (f16)v.y, (f16)v.z, (f16)v.w };
            *(f16x4*)(wsl + row * 264 + k4 * 4) = h;
        }
        __syncthreads();
#pragma unroll
        for (int ks = 0; ks < 8; ++ks) {
            int kk = ks * 32 + (l >> 4) * 8;
            f16x8 a = *(const f16x8*)(xs + (mt * 16 + (l & 15)) * 520 + kc * 256 + kk);
#pragma unroll
            for (int j = 0; j < 4; ++j) {
                f16x8 bf = *(const f16x8*)(wsl + ((ng + j) * 16 + (l & 15)) * 264 + kk);
                acc[j] = MFMA16(a, bf, acc[j]);
            }
        }
    }
    int m0 = mt * 16 + (l >> 4) * 4;
#pragma unroll
    for (int j = 0; j < 4; ++j) {
        int n = (ng + j) * 16 + (l & 15);
        float bb = (n < 64) ? be[n] : bd[n - 64];
#pragma unroll
        for (int r = 0; r < 4; ++r)
            feats[(size_t)(bt0 + m0 + r) * 128 + n] = acc[j][r] + bb;
    }

    // ---- fused lstmT transpose-write from xs (read-only; no barrier needed:
    //      xs last written before the kc loop, protected by its barriers) ----
    {
        const int hr = tid >> 2, tg = tid & 3;       // 4 lanes -> 64 B contiguous
#pragma unroll
        for (int pass = 0; pass < 8; ++pass) {
            int h = pass * 64 + hr;
            f16x8 o;
#pragma unroll
            for (int j = 0; j < 8; ++j) o[j] = xs[(tg * 8 + j) * 520 + h];
            *(f16x8*)(lstmT + ((size_t)b * 512 + h) * 256 + t0 + tg * 8) = o;
        }
    }
}

// ---------------------------------------------------------------------------
// K4: scores = v.tanh(dec[t]+enc[e]) + vb -> softmax(e) -> ctx = P @ lstm
// FUSED (round-12): final FC computed in-block from ctxs (LDS) + lstm_out,
// writing logits directly (kills K5 and the 32 MB ctx round-trip).
// WG = (b, 32-row t-tile)
// ---------------------------------------------------------------------------
__global__ __launch_bounds__(256, 1) void k4_attn(const float* __restrict__ feats,
                                                  const f16* __restrict__ lstmT,
                                                  const float* __restrict__ vvec,
                                                  const float* __restrict__ vb,
                                                  const float* __restrict__ lstm_out,
                                                  const float* __restrict__ Wfc,
                                                  const float* __restrict__ bfc,
                                                  float* __restrict__ out)
{
    __shared__ float encf[64 * 260];   // [a][e] (transposed) -- reused as ctxs[32][516]
    __shared__ float decf[32 * 68];    // [t][a]
    __shared__ f16   p16[32 * 264];    // [t][e]
    __shared__ float vs[64];
    __shared__ float vbs;
    const int tid = threadIdx.x;
    const int b = blockIdx.x >> 3, tt = blockIdx.x & 7;
    const int t0 = tt * 32;

    for (int i = 0; i < 16; ++i) {
        int L4 = tid + i * 256;          // 4096 float4 of enc feats
        int e = L4 >> 4, a4 = (L4 & 15) * 4;
        float4 v = *(const float4*)(feats + ((size_t)b * 256 + e) * 128 + a4);
        encf[(a4 + 0) * 260 + e] = v.x;  // transpose to [a][e]
        encf[(a4 + 1) * 260 + e] = v.y;
        encf[(a4 + 2) * 260 + e] = v.z;
        encf[(a4 + 3) * 260 + e] = v.w;
    }
    for (int i = 0; i < 2; ++i) {
        int L4 = tid + i * 256;
        int tr = L4 >> 4, a4 = (L4 & 15) * 4;
        float4 v = *(const float4*)(feats + ((size_t)b * 256 + t0 + tr) * 128 + 64 + a4);
        *(float4*)(decf + tr * 68 + a4) = v;
    }
    if (tid < 64) vs[tid] = vvec[tid];
    if (tid == 0) vbs = vb[0];
    __syncthreads();

    const int wv = tid >> 6, l = tid & 63;
    // ---- scores + softmax: one wave per t-row ----
    for (int tr = wv; tr < 32; tr += 4) {
        float sc[4];
#pragma unroll
        for (int j = 0; j < 4; ++j) {
            int e = l + j * 64;
            float s = vbs;
            for (int a = 0; a < 64; ++a) {
                float x = decf[tr * 68 + a] + encf[a * 260 + e];
                s += vs[a] * (1.f - 2.f / (1.f + __expf(2.f * x)));
            }
            sc[j] = s;
        }
        float mx = fmaxf(fmaxf(sc[0], sc[1]), fmaxf(sc[2], sc[3]));
        for (int d = 1; d < 64; d <<= 1) mx = fmaxf(mx, __shfl_xor(mx, d));
        float sm = 0.f;
#pragma unroll
        for (int j = 0; j < 4; ++j) { sc[j] = __expf(sc[j] - mx); sm += sc[j]; }
        for (int d = 1; d < 64; d <<= 1) sm += __shfl_xor(sm, d);
        float inv = 1.f / sm;
#pragma unroll
        for (int j = 0; j < 4; ++j) p16[tr * 264 + l + j * 64] = (f16)(sc[j] * inv);
    }
    __syncthreads();

    // ---- context MFMA: M=32(t) N=512(h) K=256(e); wave=(kh, n-half) ----
    const int kh = wv & 1, nth = wv >> 1;
    f32x4 acc0[16], acc1[16];
#pragma unroll
    for (int j = 0; j < 16; ++j) { acc0[j] = (f32x4){0,0,0,0}; acc1[j] = (f32x4){0,0,0,0}; }
#pragma unroll
    for (int ks = 0; ks < 4; ++ks) {
        int kk = (kh * 4 + ks) * 32 + (l >> 4) * 8;
        f16x8 a0 = *(const f16x8*)(p16 + (l & 15) * 264 + kk);
        f16x8 a1 = *(const f16x8*)(p16 + ((l & 15) + 16) * 264 + kk);
#pragma unroll
        for (int j = 0; j < 16; ++j) {
            int n = (nth * 16 + j) * 16 + (l & 15);
            f16x8 bf = *(const f16x8*)(lstmT + ((size_t)b * 512 + n) * 256 + kk);
            acc0[j] = MFMA16(a0, bf, acc0[j]);
            acc1[j] = MFMA16(a1, bf, acc1[j]);
        }
    }
    float* ctxs = encf;                  // reuse (encf dead now)
    __syncthreads();
    const int m0 = (l >> 4) * 4, nn = (l & 15);
    if (kh == 0) {
#pragma unroll
        for (int j = 0; j < 16; ++j) {
            int n = (nth * 16 + j) * 16 + nn;
#pragma unroll
            for (int r = 0; r < 4; ++r) {
                ctxs[(m0 + r) * 516 + n]      = acc0[j][r];
                ctxs[(16 + m0 + r) * 516 + n] = acc1[j][r];
            }
        }
    }
    __syncthreads();
    if (kh == 1) {
#pragma unroll
        for (int j = 0; j < 16; ++j) {
            int n = (nth * 16 + j) * 16 + nn;
#pragma unroll
            for (int r = 0; r < 4; ++r) {
                ctxs[(m0 + r) * 516 + n]      += acc0[j][r];
                ctxs[(16 + m0 + r) * 516 + n] += acc1[j][r];
            }
        }
    }
    __syncthreads();

    // ---- fused FC: logits[t0+tr][o] = [lstm||ctx] . Wfc[o] + bfc[o] ----
    {
        const int tr = tid >> 3, o = tid & 7;
        if (o < 7) {
            float accf = bfc[o];
            const float* xl = lstm_out + ((size_t)b * 256 + t0 + tr) * 512;
            const float* w1 = Wfc + (size_t)o * 1024;
            for (int k = 0; k < 512; k += 4) {
                float4 xv = *(const float4*)(xl + k);
                float4 wv = *(const float4*)(w1 + k);
                accf += xv.x * wv.x + xv.y * wv.y + xv.z * wv.z + xv.w * wv.w;
            }
            const float* xc = ctxs + tr * 516;
            for (int k = 0; k < 512; k += 4) {
                float4 xv = *(const float4*)(xc + k);
                float4 wv = *(const float4*)(w1 + 512 + k);
                accf += xv.x * wv.x + xv.y * wv.y + xv.z * wv.z + xv.w * wv.w;
            }
            out[((size_t)b * 256 + t0 + tr) * 7 + o] = accf;
        }
    }
}

// ---------------------------------------------------------------------------
extern "C" void kernel_launch(void* const* d_in, const int* in_sizes, int n_in,
                              void* d_out, int out_size, void* d_ws, size_t ws_size,
                              hipStream_t stream)
{
    (void)in_sizes; (void)n_in; (void)out_size;
    if (ws_size < WS_NEEDED) return;  // would fail validation loudly, not corrupt

    const int*   ids = (const int*)d_in[0];
    const float* emb = (const float*)d_in[1];
    const float* Wih = (const float*)d_in[2];
    const float* Whh = (const float*)d_in[3];
    const float* bih = (const float*)d_in[4];
    const float* bhh = (const float*)d_in[5];
    const float* We  = (const float*)d_in[6];
    const float* be  = (const float*)d_in[7];
    const float* Wd  = (const float*)d_in[8];
    const float* bd  = (const float*)d_in[9];
    const float* vv  = (const float*)d_in[10];
    const float* vb  = (const float*)d_in[11];
    const float* Wfc = (const float*)d_in[12];
    const float* bfc = (const float*)d_in[13];

    char* ws = (char*)d_ws;
    float* Xg    = (float*)(ws + OFF_XG);
    float* lstm  = (float*)(ws + OFF_LSTM);
    float* feats = (float*)(ws + OFF_FEATS);
    f16*   lstmT = (f16*)(ws + OFF_LT16);
    unsigned int* Hpk = (unsigned int*)(ws + OFF_HPK);

    // Tag-safe init EVERY launch (also clears cross-replay staleness):
    //   buf0 = 0x00... -> tag 0 AND the genuine H(0)=0 input for step 0
    //   buf1 = 0xFF... -> tag 1, which step 1 (expecting tag 0) must wait out
    hipMemsetAsync(Hpk,          0x00, 65536, stream);
    hipMemsetAsync(Hpk + 16384,  0xFF, 65536, stream);

    k1_xg   <<<dim3(32, 64), 256, 0, stream>>>(ids, emb, Wih, bih, bhh, Xg);
    k2_lstm <<<dim3(32),     512, 0, stream>>>(Whh, Xg, Hpk, lstm);
    k3_feats<<<dim3(256),    256, 0, stream>>>(lstm, We, be, Wd, bd, feats, lstmT);
    k4_attn <<<dim3(256),    256, 0, stream>>>(feats, lstmT, vv, vb, lstm, Wfc, bfc,
                                               (float*)d_out);
}

// Round 13
// 1099.523 us; speedup vs baseline: 1.1363x; 1.0197x over previous
//
#include <hip/hip_runtime.h>

// ---------------------------------------------------------------------------
// LSTM + Bahdanau attention, MI355X (gfx950)
// B=32, T=256, IN=256, HID=512, ATTN=64, OUT=7
// ---------------------------------------------------------------------------

typedef _Float16 f16;
typedef _Float16 f16x4 __attribute__((ext_vector_type(4)));
typedef _Float16 f16x8 __attribute__((ext_vector_type(8)));
typedef float    f32x4 __attribute__((ext_vector_type(4)));

#define MFMA16(a, b, c) __builtin_amdgcn_mfma_f32_16x16x32_f16((a), (b), (c), 0, 0, 0)

__device__ __forceinline__ float sigm_f(float x) { return 1.f / (1.f + __expf(-x)); }
__device__ __forceinline__ float tanh_f(float x) { return 1.f - 2.f / (1.f + __expf(2.f * x)); }

// ws offsets (bytes)
#define OFF_XG    0ull            // f32 [256][32][2048]  = 67108864  (t, b, gate-row p)
#define OFF_LSTM  67108864ull     // f32 [32][256][512]   = 16777216
#define OFF_FEATS 83886080ull     // f32 [32][256][128]   = 4194304
#define OFF_LT16  88080384ull     // f16 [32][512][256]   = 8388608
#define OFF_HPK   96468992ull     // u32 [2][32][512]     = 131072  (packed hh|hl H, tagged)
#define WS_NEEDED 96731392ull

// ---------------------------------------------------------------------------
// K1: Xg[t][b][p] = sum_k Wih[r(p)][k]*emb[ids[b][t]][k] + bih[r]+bhh[r]
//     p = w*32 + q*8 + u  <->  r = q*512 + 8*w + u   (w = blockIdx.y)
// Round-13: also initializes Hpk (buf0=0x00 tag0/H(0)=0, buf1=0xFF tag1)
// from blocks with blockIdx.x==0 -- replaces the two hipMemsetAsync nodes.
// Visibility to K2: same kernel-boundary L2 writeback that makes Xg visible.
// ---------------------------------------------------------------------------
__global__ __launch_bounds__(256) void k1_xg(const int* __restrict__ ids,
                                             const float* __restrict__ emb,
                                             const float* __restrict__ Wih,
                                             const float* __restrict__ bih,
                                             const float* __restrict__ bhh,
                                             float* __restrict__ Xg,
                                             unsigned int* __restrict__ Hpk)
{
    __shared__ f16   xs[32 * 264];     // x tile   [b][k], pad +8 f16
    __shared__ f16   wsl[32 * 264];    // Wih tile [p_local][k]
    __shared__ float biasl[32];
    __shared__ int   idsl[32];
    __shared__ float outb[32 * 33];    // [p_local][b] staging
    const int tid = threadIdx.x;
    const int tb = blockIdx.x, w = blockIdx.y;

    // ---- fused Hpk init (64 blocks x 256 threads == 16384 dwords/buffer) ----
    if (tb == 0) {
        int g = w * 256 + tid;
        Hpk[g]          = 0u;           // buf0: tag 0 AND genuine H(0)=0
        Hpk[16384 + g]  = 0xFFFFFFFFu;  // buf1: tag 1 blocks step 1
    }

    // stage Wih slice (32 rows x 256) as f16
    for (int i = 0; i < 8; ++i) {
        int L4 = tid + i * 256;              // 2048 float4
        int row = L4 >> 6, k4 = L4 & 63;
        int r = (row >> 3) * 512 + 8 * w + (row & 7);
        float4 v = *(const float4*)(Wih + (size_t)r * 256 + k4 * 4);
        f16x4 h = { (f16)v.x, (f16)v.y, (f16)v.z, (f16)v.w };
        *(f16x4*)(wsl + row * 264 + k4 * 4) = h;
    }
    if (tid < 32) {
        int r = (tid >> 3) * 512 + 8 * w + (tid & 7);
        biasl[tid] = bih[r] + bhh[r];
    }

    const int wv = tid >> 6, l = tid & 63;
    const int mt = wv >> 1, nt = wv & 1;
    const int ar = (l & 15) + mt * 16;
    const int bc = (l & 15) + nt * 16;
    const int kc = (l >> 4) * 8;

    for (int tt = 0; tt < 8; ++tt) {
        int t = tb * 8 + tt;
        __syncthreads();                     // W staged / prev iter consumed
        if (tid < 32) idsl[tid] = ids[tid * 256 + t];
        __syncthreads();
        for (int i = 0; i < 8; ++i) {
            int L4 = tid + i * 256;
            int b = L4 >> 6, k4 = L4 & 63;
            float4 v = *(const float4*)(emb + (size_t)idsl[b] * 256 + k4 * 4);
            f16x4 h = { (f16)v.x, (f16)v.y, (f16)v.z, (f16)v.w };
            *(f16x4*)(xs + b * 264 + k4 * 4) = h;
        }
        __syncthreads();

        f32x4 acc = { 0.f, 0.f, 0.f, 0.f };
#pragma unroll
        for (int ks = 0; ks < 8; ++ks) {
            f16x8 a  = *(const f16x8*)(xs  + ar * 264 + ks * 32 + kc);
            f16x8 bf = *(const f16x8*)(wsl + bc * 264 + ks * 32 + kc);
            acc = MFMA16(a, bf, acc);
        }
        float bb = biasl[bc];
#pragma unroll
        for (int r = 0; r < 4; ++r)
            outb[bc * 33 + mt * 16 + (l >> 4) * 4 + r] = acc[r] + bb;
        __syncthreads();
        {   // store [t][b][p] (transposed): thread = (b = tid>>3, pq = tid&7)
            int b = tid >> 3, pq = tid & 7;
            float4 v = { outb[(pq * 4 + 0) * 33 + b], outb[(pq * 4 + 1) * 33 + b],
                         outb[(pq * 4 + 2) * 33 + b], outb[(pq * 4 + 3) * 33 + b] };
            *(float4*)(Xg + (size_t)t * 65536 + b * 2048 + w * 32 + pq * 4) = v;
        }
    }
}

// ---------------------------------------------------------------------------
// K2: LSTM recurrence, tagged-data protocol (locked config: round-6 protocol
// + pad-36 + double-buffered pre/single barrier). 32 persistent WGs x 512
// threads; WG w owns units [16w,16w+16) (64 gate rows). Whh fragments in
// REGISTERS (hi + 4096*residual f16) -- round-13: PINNED via opaque asm
// ("+v") so the compiler cannot sink the loads into the step loop (round-6..12
// VGPR_Count=108 < the 128 VGPRs the fragments need proved they were being
// re-fetched from memory on the serial critical path every step).
// Waves = (mt in 2, kq in 4): wave polls/loads a DISJOINT 16-row x 128-col H
// slice. H = packed dwords  d = ((hl_bits & ~1) | tag) << 16 | hh_bits,
// tag = ((t+1)>>1)&1, ping-pong buffer; consumers poll the data itself
// (per-dword tag) with sc0 sc1 L3-coherent loads. Combined detect+fetch =
// ONE L3 traversal (rounds 7/10 proved added hops regress).
// Init (in K1 now): buf0=0x00 (tag0 = genuine H(0)=0), buf1=0xFF (tag1
// blocks step 1). Fixed per-wave poll regions + <=1-step skew => safe.
// ---------------------------------------------------------------------------
__global__ __launch_bounds__(512) void k2_lstm(const float* __restrict__ Whh,
                                               const float* __restrict__ Xg,
                                               unsigned int* __restrict__ Hpk,
                                               float* __restrict__ lstm_out)
{
    __shared__ float pre[2][4 * 64 * 36]; // [buf][kq][p_local][sample], pad 36
    const int tid = threadIdx.x;
    const int w = blockIdx.x;

    const int u16 = tid & 15, s_up = tid >> 4;        // update lane = (unit, sample)
    const int wv = tid >> 6, l = tid & 63;
    const int mt = wv >> 2, kq = wv & 3;              // wave = (m-tile, k-quarter)
    const int li = l & 15, lh = l >> 4;
    const int arow = mt * 16 + li;                    // sample row for A-fragment
    const int kcol = lh * 8;

    // ---- one-time: Whh fragments into registers (64 rows x 128 cols / wave) ----
    f16x8 bh[4][4], bl[4][4];                         // [ks][nt]
#pragma unroll
    for (int ks = 0; ks < 4; ++ks) {
#pragma unroll
        for (int nt = 0; nt < 4; ++nt) {
            int pl = nt * 16 + li;                    // p_local 0..63
            int q = (pl & 31) >> 3, u8 = pl & 7, wp = pl >> 5;
            int r = q * 512 + 16 * w + 8 * wp + u8;   // global gate row
            const float* s0 = Whh + (size_t)r * 512 + kq * 128 + ks * 32 + kcol;
            float4 v0 = *(const float4*)(s0);
            float4 v1 = *(const float4*)(s0 + 4);
            float vv[8] = { v0.x, v0.y, v0.z, v0.w, v1.x, v1.y, v1.z, v1.w };
            f16x8 hi, lo;
#pragma unroll
            for (int j = 0; j < 8; ++j) {
                hi[j] = (f16)vv[j];
                lo[j] = (f16)((vv[j] - (float)hi[j]) * 4096.f);
            }
            bh[ks][nt] = hi; bl[ks][nt] = lo;
        }
    }
    // ---- pin fragments: opaque redefinition forbids rematerialization ----
#pragma unroll
    for (int ks = 0; ks < 4; ++ks) {
#pragma unroll
        for (int nt = 0; nt < 4; ++nt) {
            asm volatile("" : "+v"(bh[ks][nt]));
            asm volatile("" : "+v"(bl[ks][nt]));
        }
    }

    // ---- Xg offsets for the update thread's 4 gates; prefetch t=0 ----
    int xoff[4];
    float xg_c[4], xg_n[4];
#pragma unroll
    for (int q = 0; q < 4; ++q) {
        int pl = 32 * (u16 >> 3) + 8 * q + (u16 & 7);
        xoff[q] = s_up * 2048 + 64 * w + pl;
        xg_c[q] = Xg[xoff[q]];                        // t = 0
    }

    float c = 0.f;

    for (int t = 0; t < 256; ++t) {
        const int rbuf = t & 1;
        const unsigned e = (unsigned)((t >> 1) & 1);
        const unsigned int* Hr = Hpk + rbuf * 16384 + arow * 512 + kq * 128 + kcol;
        float* prebuf = pre[t & 1];

        // ---- poll-and-load: re-load this wave's slice until all tags == e ----
        float4 P[4], Q[4];
        for (;;) {
#pragma unroll
            for (int ks = 0; ks < 4; ++ks) {
                asm volatile("global_load_dwordx4 %0, %1, off sc0 sc1"
                             : "=v"(P[ks]) : "v"(Hr + ks * 32));
                asm volatile("global_load_dwordx4 %0, %1, off sc0 sc1"
                             : "=v"(Q[ks]) : "v"(Hr + ks * 32 + 4));
            }
            asm volatile("s_waitcnt vmcnt(0)" ::: "memory");
            __builtin_amdgcn_sched_barrier(0);
            unsigned av = 0xFFFFFFFFu, ov = 0u;
#pragma unroll
            for (int ks = 0; ks < 4; ++ks) {
                unsigned m0 = __float_as_uint(P[ks].x) & __float_as_uint(P[ks].y)
                            & __float_as_uint(P[ks].z) & __float_as_uint(P[ks].w);
                unsigned m1 = __float_as_uint(Q[ks].x) & __float_as_uint(Q[ks].y)
                            & __float_as_uint(Q[ks].z) & __float_as_uint(Q[ks].w);
                unsigned o0 = __float_as_uint(P[ks].x) | __float_as_uint(P[ks].y)
                            | __float_as_uint(P[ks].z) | __float_as_uint(P[ks].w);
                unsigned o1 = __float_as_uint(Q[ks].x) | __float_as_uint(Q[ks].y)
                            | __float_as_uint(Q[ks].z) | __float_as_uint(Q[ks].w);
                av &= m0 & m1;
                ov |= o0 | o1;
            }
            bool fresh = e ? (((av >> 16) & 1u) == 1u) : (((ov >> 16) & 1u) == 0u);
            if (__all(fresh)) break;
            __builtin_amdgcn_s_sleep(1);
        }

        // ---- prefetch Xg for t+1 (plain loads; consumed next iteration) ----
        {
            int tn = (t < 255) ? t + 1 : 255;
            const float* xb = Xg + (size_t)tn * 65536;
#pragma unroll
            for (int q = 0; q < 4; ++q) xg_n[q] = xb[xoff[q]];
        }

        // ---- unpack + MFMA over this wave's K-quarter ----
        f32x4 acc1[4], acc2[4];
#pragma unroll
        for (int nt = 0; nt < 4; ++nt) { acc1[nt] = (f32x4){0,0,0,0}; acc2[nt] = (f32x4){0,0,0,0}; }
#pragma unroll
        for (int ks = 0; ks < 4; ++ks) {
            unsigned p0 = __float_as_uint(P[ks].x), p1 = __float_as_uint(P[ks].y),
                     p2 = __float_as_uint(P[ks].z), p3 = __float_as_uint(P[ks].w),
                     q0 = __float_as_uint(Q[ks].x), q1 = __float_as_uint(Q[ks].y),
                     q2 = __float_as_uint(Q[ks].z), q3 = __float_as_uint(Q[ks].w);
            uint4 hi4 = { __builtin_amdgcn_perm(p1, p0, 0x05040100u),
                          __builtin_amdgcn_perm(p3, p2, 0x05040100u),
                          __builtin_amdgcn_perm(q1, q0, 0x05040100u),
                          __builtin_amdgcn_perm(q3, q2, 0x05040100u) };
            uint4 lo4 = { __builtin_amdgcn_perm(p1, p0, 0x07060302u),
                          __builtin_amdgcn_perm(p3, p2, 0x07060302u),
                          __builtin_amdgcn_perm(q1, q0, 0x07060302u),
                          __builtin_amdgcn_perm(q3, q2, 0x07060302u) };
            f16x8 a1 = __builtin_bit_cast(f16x8, hi4);
            f16x8 a2 = __builtin_bit_cast(f16x8, lo4);
#pragma unroll
            for (int nt = 0; nt < 4; ++nt) {
                acc1[nt] = MFMA16(a1, bh[ks][nt], acc1[nt]);
                acc2[nt] = MFMA16(a2, bh[ks][nt], acc2[nt]);
                acc2[nt] = MFMA16(a1, bl[ks][nt], acc2[nt]);
            }
        }

        // ---- stage pre-activations into this step's LDS buffer ----
#pragma unroll
        for (int nt = 0; nt < 4; ++nt) {
            f32x4 v;
#pragma unroll
            for (int r = 0; r < 4; ++r) v[r] = acc1[nt][r] + acc2[nt][r] * (1.f / 4096.f);
            *(f32x4*)(prebuf + (kq * 64 + nt * 16 + li) * 36 + mt * 16 + lh * 4) = v;
        }
        __syncthreads();                 // pre[buf] visible; couples waves pre-store

        {   // ---- state update: thread = (u16, s_up) ----
            float z[4];
#pragma unroll
            for (int q = 0; q < 4; ++q) {
                int pl = 32 * (u16 >> 3) + 8 * q + (u16 & 7);
                z[q] = prebuf[(0 * 64 + pl) * 36 + s_up] + prebuf[(1 * 64 + pl) * 36 + s_up]
                     + prebuf[(2 * 64 + pl) * 36 + s_up] + prebuf[(3 * 64 + pl) * 36 + s_up]
                     + xg_c[q];
            }
            float ig = sigm_f(z[0]), fg = sigm_f(z[1]);
            float gg = tanh_f(z[2]), og = sigm_f(z[3]);
            c = fg * c + ig * gg;
            float h = og * tanh_f(c);
            f16 hh = (f16)h;
            f16 hl = (f16)((h - (float)hh) * 4096.f);
            int uu = 16 * w + u16;
            if (t < 255) {
                unsigned hhb = (unsigned)__builtin_bit_cast(unsigned short, hh);
                unsigned hlb = (unsigned)__builtin_bit_cast(unsigned short, hl);
                unsigned wtag = (unsigned)(((t + 1) >> 1) & 1);
                unsigned d = (((hlb & 0xFFFEu) | wtag) << 16) | hhb;
                asm volatile("global_store_dword %0, %1, off sc0 sc1"
                             :: "v"(Hpk + ((t + 1) & 1) * 16384 + s_up * 512 + uu),
                                "v"(d) : "memory");
            }
            lstm_out[((size_t)s_up * 256 + t) * 512 + uu] = h;
        }
#pragma unroll
        for (int q = 0; q < 4; ++q) xg_c[q] = xg_n[q];
    }
}

// ---------------------------------------------------------------------------
// K3: feats[bt][0:64]=lstm@We.T+be ; feats[bt][64:128]=lstm@Wd.T+bd
// FUSED: also emits lstmT16 [b][h][t] from the already-staged xs f16 tile.
// ---------------------------------------------------------------------------
__global__ __launch_bounds__(256) void k3_feats(const float* __restrict__ lstm_out,
                                                const float* __restrict__ We,
                                                const float* __restrict__ be,
                                                const float* __restrict__ Wd,
                                                const float* __restrict__ bd,
                                                float* __restrict__ feats,
                                                f16* __restrict__ lstmT)
{
    __shared__ f16 xs[32 * 520];       // [m][k] full K=512
    __shared__ f16 wsl[128 * 264];     // [n][k-chunk 256]
    const int tid = threadIdx.x;
    const int bt0 = blockIdx.x * 32;
    const int b = bt0 >> 8, t0 = bt0 & 255;

    for (int i = 0; i < 16; ++i) {
        int L4 = tid + i * 256;
        int row = L4 >> 7, k4 = L4 & 127;
        float4 v = *(const float4*)(lstm_out + (size_t)(bt0 + row) * 512 + k4 * 4);
        f16x4 h = { (f16)v.x, (f16)v.y, (f16)v.z, (f16)v.w };
        *(f16x4*)(xs + row * 520 + k4 * 4) = h;
    }
    const int wv = tid >> 6, l = tid & 63;
    const int mt = wv >> 1, ng = (wv & 1) * 4;
    f32x4 acc[4];
#pragma unroll
    for (int j = 0; j < 4; ++j) acc[j] = (f32x4){0,0,0,0};

    for (int kc = 0; kc < 2; ++kc) {
        __syncthreads();                 // xs ready / prev chunk consumed
        for (int i = 0; i < 32; ++i) {
            int L4 = tid + i * 256;      // 8192 float4
            int row = L4 >> 6, k4 = L4 & 63;
            const float* src = (row < 64) ? (We + (size_t)row * 512)
                                          : (Wd + (size_t)(row - 64) * 512);
            float4 v = *(const float4*)(src + kc * 256 + k4 * 4);
            f16x4 h = { (f16)v.x, (f16)v.y, (f16)v.z, (f16)v.w };
            *(f16x4*)(wsl + row * 264 + k4 * 4) = h;
        }
        __syncthreads();
#pragma unroll
        for (int ks = 0; ks < 8; ++ks) {
            int kk = ks * 32 + (l >> 4) * 8;
            f16x8 a = *(const f16x8*)(xs + (mt * 16 + (l & 15)) * 520 + kc * 256 + kk);
#pragma unroll
            for (int j = 0; j < 4; ++j) {
                f16x8 bf = *(const f16x8*)(wsl + ((ng + j) * 16 + (l & 15)) * 264 + kk);
                acc[j] = MFMA16(a, bf, acc[j]);
            }
        }
    }
    int m0 = mt * 16 + (l >> 4) * 4;
#pragma unroll
    for (int j = 0; j < 4; ++j) {
        int n = (ng + j) * 16 + (l & 15);
        float bb = (n < 64) ? be[n] : bd[n - 64];
#pragma unroll
        for (int r = 0; r < 4; ++r)
            feats[(size_t)(bt0 + m0 + r) * 128 + n] = acc[j][r] + bb;
    }

    // ---- fused lstmT transpose-write from xs ----
    {
        const int hr = tid >> 2, tg = tid & 3;       // 4 lanes -> 64 B contiguous
#pragma unroll
        for (int pass = 0; pass < 8; ++pass) {
            int h = pass * 64 + hr;
            f16x8 o;
#pragma unroll
            for (int j = 0; j < 8; ++j) o[j] = xs[(tg * 8 + j) * 520 + h];
            *(f16x8*)(lstmT + ((size_t)b * 512 + h) * 256 + t0 + tg * 8) = o;
        }
    }
}

// ---------------------------------------------------------------------------
// K4: scores = v.tanh(dec[t]+enc[e]) + vb -> softmax(e) -> ctx = P @ lstm
// FUSED: final FC from ctxs (LDS) + lstm_out, writing logits directly.
// WG = (b, 32-row t-tile)
// ---------------------------------------------------------------------------
__global__ __launch_bounds__(256, 1) void k4_attn(const float* __restrict__ feats,
                                                  const f16* __restrict__ lstmT,
                                                  const float* __restrict__ vvec,
                                                  const float* __restrict__ vb,
                                                  const float* __restrict__ lstm_out,
                                                  const float* __restrict__ Wfc,
                                                  const float* __restrict__ bfc,
                                                  float* __restrict__ out)
{
    __shared__ float encf[64 * 260];   // [a][e] (transposed) -- reused as ctxs[32][516]
    __shared__ float decf[32 * 68];    // [t][a]
    __shared__ f16   p16[32 * 264];    // [t][e]
    __shared__ float vs[64];
    __shared__ float vbs;
    const int tid = threadIdx.x;
    const int b = blockIdx.x >> 3, tt = blockIdx.x & 7;
    const int t0 = tt * 32;

    for (int i = 0; i < 16; ++i) {
        int L4 = tid + i * 256;          // 4096 float4 of enc feats
        int e = L4 >> 4, a4 = (L4 & 15) * 4;
        float4 v = *(const float4*)(feats + ((size_t)b * 256 + e) * 128 + a4);
        encf[(a4 + 0) * 260 + e] = v.x;  // transpose to [a][e]
        encf[(a4 + 1) * 260 + e] = v.y;
        encf[(a4 + 2) * 260 + e] = v.z;
        encf[(a4 + 3) * 260 + e] = v.w;
    }
    for (int i = 0; i < 2; ++i) {
        int L4 = tid + i * 256;
        int tr = L4 >> 4, a4 = (L4 & 15) * 4;
        float4 v = *(const float4*)(feats + ((size_t)b * 256 + t0 + tr) * 128 + 64 + a4);
        *(float4*)(decf + tr * 68 + a4) = v;
    }
    if (tid < 64) vs[tid] = vvec[tid];
    if (tid == 0) vbs = vb[0];
    __syncthreads();

    const int wv = tid >> 6, l = tid & 63;
    // ---- scores + softmax: one wave per t-row ----
    for (int tr = wv; tr < 32; tr += 4) {
        float sc[4];
#pragma unroll
        for (int j = 0; j < 4; ++j) {
            int e = l + j * 64;
            float s = vbs;
            for (int a = 0; a < 64; ++a) {
                float x = decf[tr * 68 + a] + encf[a * 260 + e];
                s += vs[a] * (1.f - 2.f / (1.f + __expf(2.f * x)));
            }
            sc[j] = s;
        }
        float mx = fmaxf(fmaxf(sc[0], sc[1]), fmaxf(sc[2], sc[3]));
        for (int d = 1; d < 64; d <<= 1) mx = fmaxf(mx, __shfl_xor(mx, d));
        float sm = 0.f;
#pragma unroll
        for (int j = 0; j < 4; ++j) { sc[j] = __expf(sc[j] - mx); sm += sc[j]; }
        for (int d = 1; d < 64; d <<= 1) sm += __shfl_xor(sm, d);
        float inv = 1.f / sm;
#pragma unroll
        for (int j = 0; j < 4; ++j) p16[tr * 264 + l + j * 64] = (f16)(sc[j] * inv);
    }
    __syncthreads();

    // ---- context MFMA: M=32(t) N=512(h) K=256(e); wave=(kh, n-half) ----
    const int kh = wv & 1, nth = wv >> 1;
    f32x4 acc0[16], acc1[16];
#pragma unroll
    for (int j = 0; j < 16; ++j) { acc0[j] = (f32x4){0,0,0,0}; acc1[j] = (f32x4){0,0,0,0}; }
#pragma unroll
    for (int ks = 0; ks < 4; ++ks) {
        int kk = (kh * 4 + ks) * 32 + (l >> 4) * 8;
        f16x8 a0 = *(const f16x8*)(p16 + (l & 15) * 264 + kk);
        f16x8 a1 = *(const f16x8*)(p16 + ((l & 15) + 16) * 264 + kk);
#pragma unroll
        for (int j = 0; j < 16; ++j) {
            int n = (nth * 16 + j) * 16 + (l & 15);
            f16x8 bf = *(const f16x8*)(lstmT + ((size_t)b * 512 + n) * 256 + kk);
            acc0[j] = MFMA16(a0, bf, acc0[j]);
            acc1[j] = MFMA16(a1, bf, acc1[j]);
        }
    }
    float* ctxs = encf;                  // reuse (encf dead now)
    __syncthreads();
    const int m0 = (l >> 4) * 4, nn = (l & 15);
    if (kh == 0) {
#pragma unroll
        for (int j = 0; j < 16; ++j) {
            int n = (nth * 16 + j) * 16 + nn;
#pragma unroll
            for (int r = 0; r < 4; ++r) {
                ctxs[(m0 + r) * 516 + n]      = acc0[j][r];
                ctxs[(16 + m0 + r) * 516 + n] = acc1[j][r];
            }
        }
    }
    __syncthreads();
    if (kh == 1) {
#pragma unroll
        for (int j = 0; j < 16; ++j) {
            int n = (nth * 16 + j) * 16 + nn;
#pragma unroll
            for (int r = 0; r < 4; ++r) {
                ctxs[(m0 + r) * 516 + n]      += acc0[j][r];
                ctxs[(16 + m0 + r) * 516 + n] += acc1[j][r];
            }
        }
    }
    __syncthreads();

    // ---- fused FC: logits[t0+tr][o] = [lstm||ctx] . Wfc[o] + bfc[o] ----
    {
        const int tr = tid >> 3, o = tid & 7;
        if (o < 7) {
            float accf = bfc[o];
            const float* xl = lstm_out + ((size_t)b * 256 + t0 + tr) * 512;
            const float* w1 = Wfc + (size_t)o * 1024;
            for (int k = 0; k < 512; k += 4) {
                float4 xv = *(const float4*)(xl + k);
                float4 wv = *(const float4*)(w1 + k);
                accf += xv.x * wv.x + xv.y * wv.y + xv.z * wv.z + xv.w * wv.w;
            }
            const float* xc = ctxs + tr * 516;
            for (int k = 0; k < 512; k += 4) {
                float4 xv = *(const float4*)(xc + k);
                float4 wv = *(const float4*)(w1 + 512 + k);
                accf += xv.x * wv.x + xv.y * wv.y + xv.z * wv.z + xv.w * wv.w;
            }
            out[((size_t)b * 256 + t0 + tr) * 7 + o] = accf;
        }
    }
}

// ---------------------------------------------------------------------------
extern "C" void kernel_launch(void* const* d_in, const int* in_sizes, int n_in,
                              void* d_out, int out_size, void* d_ws, size_t ws_size,
                              hipStream_t stream)
{
    (void)in_sizes; (void)n_in; (void)out_size;
    if (ws_size < WS_NEEDED) return;  // would fail validation loudly, not corrupt

    const int*   ids = (const int*)d_in[0];
    const float* emb = (const float*)d_in[1];
    const float* Wih = (const float*)d_in[2];
    const float* Whh = (const float*)d_in[3];
    const float* bih = (const float*)d_in[4];
    const float* bhh = (const float*)d_in[5];
    const float* We  = (const float*)d_in[6];
    const float* be  = (const float*)d_in[7];
    const float* Wd  = (const float*)d_in[8];
    const float* bd  = (const float*)d_in[9];
    const float* vv  = (const float*)d_in[10];
    const float* vb  = (const float*)d_in[11];
    const float* Wfc = (const float*)d_in[12];
    const float* bfc = (const float*)d_in[13];

    char* ws = (char*)d_ws;
    float* Xg    = (float*)(ws + OFF_XG);
    float* lstm  = (float*)(ws + OFF_LSTM);
    float* feats = (float*)(ws + OFF_FEATS);
    f16*   lstmT = (f16*)(ws + OFF_LT16);
    unsigned int* Hpk = (unsigned int*)(ws + OFF_HPK);

    // Hpk init is fused into K1 (blocks with blockIdx.x==0); stream order
    // K1 -> K2 plus kernel-boundary L2 writeback gives K2 a clean view.
    k1_xg   <<<dim3(32, 64), 256, 0, stream>>>(ids, emb, Wih, bih, bhh, Xg, Hpk);
    k2_lstm <<<dim3(32),     512, 0, stream>>>(Whh, Xg, Hpk, lstm);
    k3_feats<<<dim3(256),    256, 0, stream>>>(lstm, We, be, Wd, bd, feats, lstmT);
    k4_attn <<<dim3(256),    256, 0, stream>>>(feats, lstmT, vv, vb, lstm, Wfc, bfc,
                                               (float*)d_out);
}